// Round 1
// baseline (1453.206 us; speedup 1.0000x reference)
//
#include <hip/hip_runtime.h>
#include <math.h>

#define BB 16
#define CC 256
#define COo 256
#define HH 32
#define WW 32
#define HW 1024
#define OHH 64
#define OWW 64

// ---------------- offset conv: 3x3, pad 1, C=256 -> 18 ----------------
__global__ __launch_bounds__(576) void k_offset_conv(const float* __restrict__ x,
                                                     const float* __restrict__ w_off,
                                                     const float* __restrict__ b_off,
                                                     float* __restrict__ off) {
    int h = blockIdx.x, b = blockIdx.y;
    int t = threadIdx.x;
    int oc = t >> 5, w = t & 31;           // oc < 18, w < 32
    __shared__ float xl[32][3][34];        // 32 channels x 3 rows x (32+2 pad)
    float acc = b_off[oc];
    for (int cc = 0; cc < CC; cc += 32) {
        __syncthreads();
        for (int idx = t; idx < 32 * 3 * 34; idx += 576) {
            int col = idx % 34;
            int row = (idx / 34) % 3;
            int ci  = idx / (34 * 3);
            float v = 0.f;
            int hy = h + row - 1;
            int wx = col - 1;
            if (hy >= 0 && hy < HH && wx >= 0 && wx < WW)
                v = x[((b * CC + cc + ci) * HH + hy) * WW + wx];
            xl[ci][row][col] = v;
        }
        __syncthreads();
        for (int ci = 0; ci < 32; ++ci) {
            const float* wp = w_off + (oc * CC + cc + ci) * 9;
            acc += xl[ci][0][w]     * wp[0] + xl[ci][0][w + 1] * wp[1] + xl[ci][0][w + 2] * wp[2]
                 + xl[ci][1][w]     * wp[3] + xl[ci][1][w + 1] * wp[4] + xl[ci][1][w + 2] * wp[5]
                 + xl[ci][2][w]     * wp[6] + xl[ci][2][w + 1] * wp[7] + xl[ci][2][w + 2] * wp[8];
        }
    }
    off[((b * 18 + oc) * HH + h) * WW + w] = acc;
}

// ---------------- weight transposes ----------------
// w_def [co][c][k] -> wdT [c][k][co]
__global__ void k_transpose_wdef(const float* __restrict__ w_def, float* __restrict__ wdT) {
    int i = blockIdx.x * 256 + threadIdx.x;  // 589824 total, exact grid
    int k = i % 9;
    int c = (i / 9) & 255;
    int co = i / (9 * 256);
    wdT[(c * 9 + k) * 256 + co] = w_def[i];
}

// w_dc [ci][co][kh][kw] -> wdcT [ci][kh][kw][co]
__global__ void k_transpose_wdc(const float* __restrict__ w_dc, float* __restrict__ wdcT) {
    int i = blockIdx.x * 256 + threadIdx.x;  // 1048576 total, exact grid
    int kw = i & 3;
    int kh = (i >> 2) & 3;
    int co = (i >> 4) & 255;
    int ci = i >> 12;
    wdcT[(ci * 16 + kh * 4 + kw) * 256 + co] = w_dc[i];
}

// ---------------- deformable conv ----------------
// grid (16 tiles, 16 b), 512 threads. tile = 64 positions = 2 rows.
// thread: co in {co0, co0+128}, co0 = t&127 ; pos group pg = t>>7 -> 16 positions
__global__ __launch_bounds__(512) void k_deform(const float* __restrict__ x,
                                                const float* __restrict__ off,
                                                const float* __restrict__ wdT,
                                                const float* __restrict__ b_def,
                                                float* __restrict__ y1) {
    int tile = blockIdx.x, b = blockIdx.y;
    int t = threadIdx.x;
    int h0 = tile * 2;
    __shared__ float xl[1024];
    __shared__ float sl[9 * 64];
    __shared__ int   my0[9 * 64];
    __shared__ int   mx0[9 * 64];
    __shared__ float mwy[9 * 64];
    __shared__ float mwx[9 * 64];
    __shared__ float lds2[128 * 65];

    // per-tap bilinear metadata (once per block)
    for (int idx = t; idx < 576; idx += 512) {
        int k = idx / 64, pos = idx % 64;
        int h = h0 + (pos >> 5), w = pos & 31;
        float dy = off[((b * 18 + 2 * k) * HH + h) * WW + w];
        float dx = off[((b * 18 + 2 * k + 1) * HH + h) * WW + w];
        float py = (float)h + (float)(k / 3 - 1) + dy;
        float px = (float)w + (float)(k % 3 - 1) + dx;
        float y0 = floorf(py), x0f = floorf(px);
        my0[idx] = (int)y0;
        mx0[idx] = (int)x0f;
        mwy[idx] = py - y0;
        mwx[idx] = px - x0f;
    }

    int co0 = t & 127;
    int pg  = t >> 7;
    int posb = pg * 16;
    float acc[2][16];
#pragma unroll
    for (int j = 0; j < 2; ++j)
#pragma unroll
        for (int i = 0; i < 16; ++i) acc[j][i] = 0.f;

    for (int c = 0; c < CC; ++c) {
        __syncthreads();  // protect xl & sl from previous iteration readers
        // stage x[b,c,:,:] (1024 floats)
        reinterpret_cast<float2*>(xl)[t] =
            reinterpret_cast<const float2*>(x + (size_t)(b * CC + c) * HW)[t];
        __syncthreads();
        // compute sampled values s[k][pos]
        for (int idx = t; idx < 576; idx += 512) {
            int y0 = my0[idx], x0 = mx0[idx];
            float wy = mwy[idx], wx = mwx[idx];
            float v = 0.f;
            bool ya = (y0 >= 0) & (y0 < HH);
            bool yb = (y0 + 1 >= 0) & (y0 + 1 < HH);
            bool xa = (x0 >= 0) & (x0 < WW);
            bool xb = (x0 + 1 >= 0) & (x0 + 1 < WW);
            if (ya && xa) v += (1.f - wy) * (1.f - wx) * xl[y0 * WW + x0];
            if (ya && xb) v += (1.f - wy) * wx         * xl[y0 * WW + x0 + 1];
            if (yb && xa) v += wy * (1.f - wx)         * xl[(y0 + 1) * WW + x0];
            if (yb && xb) v += wy * wx                  * xl[(y0 + 1) * WW + x0 + 1];
            sl[idx] = v;
        }
        __syncthreads();
        const float* wrow = wdT + c * 2304;
#pragma unroll
        for (int k = 0; k < 9; ++k) {
            float wa = wrow[k * 256 + co0];
            float wb = wrow[k * 256 + co0 + 128];
#pragma unroll
            for (int pp = 0; pp < 16; pp += 4) {
                float4 s4 = *reinterpret_cast<const float4*>(&sl[k * 64 + posb + pp]);
                acc[0][pp + 0] += wa * s4.x; acc[1][pp + 0] += wb * s4.x;
                acc[0][pp + 1] += wa * s4.y; acc[1][pp + 1] += wb * s4.y;
                acc[0][pp + 2] += wa * s4.z; acc[1][pp + 2] += wb * s4.z;
                acc[0][pp + 3] += wa * s4.w; acc[1][pp + 3] += wb * s4.w;
            }
        }
    }

    // coalesced write-out via LDS transpose
    for (int j = 0; j < 2; ++j) {
        float bd = b_def[co0 + j * 128];
        __syncthreads();
#pragma unroll
        for (int i = 0; i < 16; ++i) lds2[co0 * 65 + posb + i] = acc[j][i] + bd;
        __syncthreads();
        for (int idx = t; idx < 128 * 64; idx += 512) {
            int cl = idx >> 6, pos = idx & 63;
            y1[((size_t)(b * COo + j * 128 + cl) * HW) + h0 * WW + pos] = lds2[cl * 65 + pos];
        }
    }
}

// ---------------- ConvTranspose2d 4x4 stride 2 pad 1 ----------------
// grid (64 oh, 16 b), 256 threads. thread: co = co0 + 64j (j<4), ow = og*16 + i
__global__ __launch_bounds__(256) void k_convt(const float* __restrict__ y1,
                                               const float* __restrict__ wdcT,
                                               float* __restrict__ out) {
    int oh = blockIdx.x, b = blockIdx.y;
    int t = threadIdx.x;
    int co0 = t & 63;
    int og  = t >> 6;
    int khA, ihA, khB, ihB;
    if (oh & 1) { khA = 0; ihA = (oh + 1) >> 1; khB = 2; ihB = (oh - 1) >> 1; }
    else        { khA = 1; ihA = oh >> 1;       khB = 3; ihB = (oh >> 1) - 1; }
    bool vA = (ihA >= 0) && (ihA < HH);
    bool vB = (ihB >= 0) && (ihB < HH);

    __shared__ float yl[2][32];
    __shared__ float lds2[64 * 65];
    float acc[4][16];
#pragma unroll
    for (int j = 0; j < 4; ++j)
#pragma unroll
        for (int i = 0; i < 16; ++i) acc[j][i] = 0.f;

    for (int ci = 0; ci < CC; ++ci) {
        __syncthreads();
        if (t < 64) {
            int pair = t >> 5, iw = t & 31;
            int ih = pair ? ihB : ihA;
            bool v = pair ? vB : vA;
            yl[pair][iw] = v ? y1[((size_t)(b * CC + ci) * HH + ih) * WW + iw] : 0.f;
        }
        __syncthreads();
        const float* wp = wdcT + (size_t)ci * 4096;
        float wv[2][4][4];
#pragma unroll
        for (int p = 0; p < 2; ++p) {
            int kh = p ? khB : khA;
#pragma unroll
            for (int kw = 0; kw < 4; ++kw)
#pragma unroll
                for (int j = 0; j < 4; ++j)
                    wv[p][kw][j] = wp[(kh * 4 + kw) * 256 + co0 + 64 * j];
        }
#pragma unroll
        for (int i = 0; i < 16; ++i) {
            int ow = og * 16 + i;
            if ((i & 1) == 0) {
                // ow even: kw=1 (iw=ow/2), kw=3 (iw=ow/2-1)
                int iwA = ow >> 1;
                int iwB = iwA - 1;
                float yA1 = yl[0][iwA], yB1 = yl[1][iwA];
                float yA3 = (iwB >= 0) ? yl[0][iwB] : 0.f;
                float yB3 = (iwB >= 0) ? yl[1][iwB] : 0.f;
#pragma unroll
                for (int j = 0; j < 4; ++j)
                    acc[j][i] += yA1 * wv[0][1][j] + yA3 * wv[0][3][j]
                               + yB1 * wv[1][1][j] + yB3 * wv[1][3][j];
            } else {
                // ow odd: kw=0 (iw=(ow+1)/2), kw=2 (iw=(ow-1)/2)
                int iw0 = (ow + 1) >> 1;
                int iw2 = iw0 - 1;
                float yA0 = (iw0 < 32) ? yl[0][iw0] : 0.f;
                float yB0 = (iw0 < 32) ? yl[1][iw0] : 0.f;
                float yA2 = yl[0][iw2], yB2 = yl[1][iw2];
#pragma unroll
                for (int j = 0; j < 4; ++j)
                    acc[j][i] += yA0 * wv[0][0][j] + yA2 * wv[0][2][j]
                               + yB0 * wv[1][0][j] + yB2 * wv[1][2][j];
            }
        }
    }

    // coalesced write-out via LDS transpose (4 chunks of 64 co)
    for (int j = 0; j < 4; ++j) {
        __syncthreads();
#pragma unroll
        for (int i = 0; i < 16; ++i) lds2[co0 * 65 + og * 16 + i] = acc[j][i];
        __syncthreads();
        for (int idx = t; idx < 4096; idx += 256) {
            int cl = idx >> 6, ow = idx & 63;
            out[(((size_t)(b * COo + j * 64 + cl)) * OHH + oh) * OWW + ow] = lds2[cl * 65 + ow];
        }
    }
}

// ---------------- BatchNorm stats (biased var) ----------------
__global__ __launch_bounds__(256) void k_bnstats(const float* __restrict__ src, int nb, int hw,
                                                 float* __restrict__ mean, float* __restrict__ rstd) {
    int ch = blockIdx.x;
    int t = threadIdx.x;
    float s = 0.f, s2 = 0.f;
    for (int b = 0; b < nb; ++b) {
        const float* p = src + ((size_t)(b * 256 + ch)) * hw;
        for (int i = t; i < hw; i += 256) {
            float v = p[i];
            s += v;
            s2 += v * v;
        }
    }
    __shared__ float rs[256], rs2[256];
    rs[t] = s; rs2[t] = s2;
    __syncthreads();
    for (int d = 128; d > 0; d >>= 1) {
        if (t < d) { rs[t] += rs[t + d]; rs2[t] += rs2[t + d]; }
        __syncthreads();
    }
    if (t == 0) {
        float n = (float)nb * (float)hw;
        float m = rs[0] / n;
        float var = rs2[0] / n - m * m;
        mean[ch] = m;
        rstd[ch] = rsqrtf(var + 1e-5f);
    }
}

// ---------------- BN normalize + SiLU, in place ----------------
__global__ __launch_bounds__(256) void k_bnsilu(float* __restrict__ data,
                                                const float* __restrict__ mean,
                                                const float* __restrict__ rstd,
                                                const float* __restrict__ gamma,
                                                const float* __restrict__ beta,
                                                int hw, long total) {
    long i = (long)blockIdx.x * 256 + threadIdx.x;
    if (i < total) {
        int ch = (int)((i / hw) & 255);
        float v = data[i];
        float y = gamma[ch] * (v - mean[ch]) * rstd[ch] + beta[ch];
        data[i] = y / (1.f + expf(-y));
    }
}

extern "C" void kernel_launch(void* const* d_in, const int* in_sizes, int n_in,
                              void* d_out, int out_size, void* d_ws, size_t ws_size,
                              hipStream_t stream) {
    const float* x      = (const float*)d_in[0];
    const float* w_off  = (const float*)d_in[1];
    const float* b_off  = (const float*)d_in[2];
    const float* w_def  = (const float*)d_in[3];
    const float* b_def  = (const float*)d_in[4];
    const float* gamma1 = (const float*)d_in[5];
    const float* beta1  = (const float*)d_in[6];
    const float* w_dc   = (const float*)d_in[7];
    const float* gamma2 = (const float*)d_in[8];
    const float* beta2  = (const float*)d_in[9];
    float* out = (float*)d_out;

    float* ws    = (float*)d_ws;
    float* off   = ws;                       // 16*18*1024 = 294912
    float* y1    = off + 294912;             // 16*256*1024 = 4194304
    float* wdT   = y1 + 4194304;             // 589824
    float* wdcT  = wdT + 589824;             // 1048576
    float* stats = wdcT + 1048576;           // 1024
    float* mean1 = stats, *rstd1 = stats + 256, *mean2 = stats + 512, *rstd2 = stats + 768;

    k_offset_conv<<<dim3(32, 16), 576, 0, stream>>>(x, w_off, b_off, off);
    k_transpose_wdef<<<2304, 256, 0, stream>>>(w_def, wdT);
    k_transpose_wdc<<<4096, 256, 0, stream>>>(w_dc, wdcT);
    k_deform<<<dim3(16, 16), 512, 0, stream>>>(x, off, wdT, b_def, y1);
    k_bnstats<<<256, 256, 0, stream>>>(y1, BB, HW, mean1, rstd1);
    k_bnsilu<<<16384, 256, 0, stream>>>(y1, mean1, rstd1, gamma1, beta1, HW, 4194304L);
    k_convt<<<dim3(64, 16), 256, 0, stream>>>(y1, wdcT, out);
    k_bnstats<<<256, 256, 0, stream>>>(out, BB, OHH * OWW, mean2, rstd2);
    k_bnsilu<<<65536, 256, 0, stream>>>(out, mean2, rstd2, gamma2, beta2, OHH * OWW, 16777216L);
}

// Round 2
// 577.359 us; speedup vs baseline: 2.5170x; 2.5170x over previous
//
#include <hip/hip_runtime.h>
#include <math.h>

#ifdef __has_builtin
#if __has_builtin(__builtin_amdgcn_global_load_lds)
#define HAS_GLL 1
#endif
#endif
#ifndef HAS_GLL
#define HAS_GLL 0
#endif

typedef __attribute__((ext_vector_type(8))) short short8v;
typedef __attribute__((ext_vector_type(4))) float float4v;

__device__ __forceinline__ unsigned short f2bf(float f) {
    unsigned int u = __float_as_uint(f);
    u += 0x7fffu + ((u >> 16) & 1u);
    return (unsigned short)(u >> 16);
}

// wave stages 1KB into LDS: lane i -> ldsbase + 16*i, from per-lane gsrc (16B each)
__device__ __forceinline__ void stage1k(const void* gsrc, void* ldsbase) {
#if HAS_GLL
    __builtin_amdgcn_global_load_lds((const __attribute__((address_space(1))) unsigned int*)gsrc,
                                     (__attribute__((address_space(3))) unsigned int*)ldsbase,
                                     16, 0, 0);
#else
    int lane = threadIdx.x & 63;
    *(float4*)((char*)ldsbase + lane * 16) = *(const float4*)gsrc;
#endif
}

// ---------------- offset conv: 3x3, pad 1, C=256 -> 18 (unchanged, fp32) ----------------
__global__ __launch_bounds__(576) void k_offset_conv(const float* __restrict__ x,
                                                     const float* __restrict__ w_off,
                                                     const float* __restrict__ b_off,
                                                     float* __restrict__ off) {
    int h = blockIdx.x, b = blockIdx.y;
    int t = threadIdx.x;
    int oc = t >> 5, w = t & 31;
    __shared__ float xl[32][3][34];
    float acc = b_off[oc];
    for (int cc = 0; cc < 256; cc += 32) {
        __syncthreads();
        for (int idx = t; idx < 32 * 3 * 34; idx += 576) {
            int col = idx % 34;
            int row = (idx / 34) % 3;
            int ci  = idx / (34 * 3);
            float v = 0.f;
            int hy = h + row - 1;
            int wx = col - 1;
            if (hy >= 0 && hy < 32 && wx >= 0 && wx < 32)
                v = x[((b * 256 + cc + ci) * 32 + hy) * 32 + wx];
            xl[ci][row][col] = v;
        }
        __syncthreads();
        for (int ci = 0; ci < 32; ++ci) {
            const float* wp = w_off + (oc * 256 + cc + ci) * 9;
            acc += xl[ci][0][w]     * wp[0] + xl[ci][0][w + 1] * wp[1] + xl[ci][0][w + 2] * wp[2]
                 + xl[ci][1][w]     * wp[3] + xl[ci][1][w + 1] * wp[4] + xl[ci][1][w + 2] * wp[5]
                 + xl[ci][2][w]     * wp[6] + xl[ci][2][w + 1] * wp[7] + xl[ci][2][w + 2] * wp[8];
        }
    }
    off[((b * 18 + oc) * 32 + h) * 32 + w] = acc;
}

// ---------------- weight preps (fp32 -> bf16) ----------------
// A1[co][c*9+k] = bf16(w_def) — same flat order
__global__ void k_prep_a1(const float* __restrict__ w_def, unsigned short* __restrict__ A1) {
    int i = blockIdx.x * 256 + threadIdx.x;  // 589824
    A1[i] = f2bf(w_def[i]);
}

// A2[p][co][tap*256+ci] = bf16(w_dc[ci][co][kh][kw]) with parity/tap mapping
__global__ void k_prep_a2(const float* __restrict__ w_dc, unsigned short* __restrict__ A2) {
    int i = blockIdx.x * 256 + threadIdx.x;  // 1048576
    int ci = i & 255;
    int tq = (i >> 8) & 3;
    int co = (i >> 10) & 255;
    int p  = i >> 18;
    int ph = p >> 1, pw = p & 1;
    int ty = tq >> 1, tx = tq & 1;
    int kh = 2 * ty + 1 - ph;
    int kw = 2 * tx + 1 - pw;
    A2[i] = f2bf(w_dc[((ci * 256 + co) * 4 + kh) * 4 + kw]);
}

// ---------------- bilinear sampler: S[n][c*9+k] bf16 ----------------
__global__ __launch_bounds__(512) void k_sample(const float* __restrict__ x,
                                                const float* __restrict__ off,
                                                unsigned short* __restrict__ S) {
    int tile = blockIdx.x, b = blockIdx.y;
    int t = threadIdx.x;
    int h0 = tile * 2;
    int n0 = b * 1024 + tile * 64;
    __shared__ int   my0[576];
    __shared__ int   mx0[576];
    __shared__ float mwy[576];
    __shared__ float mwx[576];
    __shared__ __align__(16) float xpl[8 * 1024];
    __shared__ __align__(16) unsigned short sS[64 * 72];

    for (int idx = t; idx < 576; idx += 512) {
        int k = idx >> 6, pos = idx & 63;
        int h = h0 + (pos >> 5), w = pos & 31;
        float dy = off[((b * 18 + 2 * k) * 32 + h) * 32 + w];
        float dx = off[((b * 18 + 2 * k + 1) * 32 + h) * 32 + w];
        float py = (float)(h + (k / 3) - 1) + dy;
        float px = (float)(w + (k % 3) - 1) + dx;
        float fy = floorf(py), fx = floorf(px);
        my0[idx] = (int)fy;
        mx0[idx] = (int)fx;
        mwy[idx] = py - fy;
        mwx[idx] = px - fx;
    }

    for (int cc = 0; cc < 256; cc += 8) {
        __syncthreads();
        for (int idx = t; idx < 2048; idx += 512) {
            int c_l = idx >> 8, wi = (idx & 255) * 4;
            *(float4*)&xpl[c_l * 1024 + wi] =
                *(const float4*)&x[(size_t)((b * 256 + cc + c_l) * 1024) + wi];
        }
        __syncthreads();
        for (int idx = t; idx < 4608; idx += 512) {
            int pos = idx / 72;
            int kc = idx - pos * 72;
            int c_l = kc / 9;
            int k = kc - c_l * 9;
            int m = (k << 6) + pos;
            int y0 = my0[m], x0 = mx0[m];
            float wy = mwy[m], wx = mwx[m];
            const float* pl = xpl + c_l * 1024;
            float v = 0.f;
            bool ya = (y0 >= 0) && (y0 < 32);
            bool yb = (y0 >= -1) && (y0 < 31);
            bool xa = (x0 >= 0) && (x0 < 32);
            bool xb = (x0 >= -1) && (x0 < 31);
            if (ya && xa) v += (1.f - wy) * (1.f - wx) * pl[y0 * 32 + x0];
            if (ya && xb) v += (1.f - wy) * wx         * pl[y0 * 32 + x0 + 1];
            if (yb && xa) v += wy * (1.f - wx)         * pl[(y0 + 1) * 32 + x0];
            if (yb && xb) v += wy * wx                  * pl[(y0 + 1) * 32 + x0 + 1];
            sS[pos * 72 + kc] = f2bf(v);
        }
        __syncthreads();
        for (int idx = t; idx < 576; idx += 512) {
            int row = idx / 9, ch = idx - row * 9;
            float4 vv = *(const float4*)((const char*)sS + row * 144 + ch * 16);
            *(float4*)(S + (size_t)(n0 + row) * 2304 + cc * 9 + ch * 8) = vv;
        }
    }
}

// ---------------- GEMM1: y1[co][n] = sum_K A1[co][K] * S[n][K], K=2304 ----------------
// BM=128 (blockIdx.y of 2), BN=64 (blockIdx.x of 256), 4 waves (2m x 2n), wave=64co x 32n
__global__ __launch_bounds__(256) void k_gemm1(const unsigned short* __restrict__ A1,
                                               const unsigned short* __restrict__ S,
                                               const float* __restrict__ b_def,
                                               float* __restrict__ y1) {
    int nb = blockIdx.x, mb = blockIdx.y;
    int t = threadIdx.x;
    int lane = t & 63, wid = t >> 6;
    int wm = wid >> 1, wn = wid & 1;
    __shared__ __align__(16) unsigned short As[128 * 32];
    __shared__ __align__(16) unsigned short Bs[64 * 32];
    int m0 = mb * 128, n0 = nb * 64;
    float4v acc[4][2];
    float4v z = {0.f, 0.f, 0.f, 0.f};
#pragma unroll
    for (int i = 0; i < 4; ++i) { acc[i][0] = z; acc[i][1] = z; }
    int rQ = lane >> 2, qA = lane & 3;
    const unsigned short* gA0 = A1 + (size_t)(m0 + wid * 32 + rQ) * 2304 + qA * 8;
    const unsigned short* gA1 = gA0 + (size_t)16 * 2304;
    const unsigned short* gB0 = S + (size_t)(n0 + wid * 16 + rQ) * 2304 + qA * 8;
    unsigned short* lA0 = As + wid * 32 * 32;
    unsigned short* lA1 = As + (wid * 32 + 16) * 32;
    unsigned short* lB0 = Bs + wid * 16 * 32;
    int g = lane >> 4, l15 = lane & 15;
    for (int s = 0; s < 72; ++s) {
        __syncthreads();
        stage1k(gA0 + s * 32, lA0);
        stage1k(gA1 + s * 32, lA1);
        stage1k(gB0 + s * 32, lB0);
        __syncthreads();
        short8v a[4], bb[2];
#pragma unroll
        for (int mi = 0; mi < 4; ++mi)
            a[mi] = *(const short8v*)((const char*)As + ((wm * 64 + mi * 16 + l15) * 64 + g * 16));
#pragma unroll
        for (int ni = 0; ni < 2; ++ni)
            bb[ni] = *(const short8v*)((const char*)Bs + ((wn * 32 + ni * 16 + l15) * 64 + g * 16));
#pragma unroll
        for (int mi = 0; mi < 4; ++mi)
#pragma unroll
            for (int ni = 0; ni < 2; ++ni)
                acc[mi][ni] = __builtin_amdgcn_mfma_f32_16x16x32_bf16(a[mi], bb[ni], acc[mi][ni], 0, 0, 0);
    }
    int b = n0 >> 10;
    int posb = n0 & 1023;
#pragma unroll
    for (int mi = 0; mi < 4; ++mi) {
#pragma unroll
        for (int r = 0; r < 4; ++r) {
            int co = m0 + wm * 64 + mi * 16 + g * 4 + r;
            float bv = b_def[co];
            float* dst = y1 + ((size_t)(b * 256 + co) << 10) + posb;
#pragma unroll
            for (int ni = 0; ni < 2; ++ni)
                dst[wn * 32 + ni * 16 + l15] = acc[mi][ni][r] + bv;
        }
    }
}

// ---------------- GEMM2: convT by parity. out[co][n] = sum_K A2p[co][K] * B[n][K] ----------------
// K = tap*256 + ci (32 steps of 32); B reg-staged from padded bf16 y1pb with tap shifts.
__global__ __launch_bounds__(256) void k_gemm2(const unsigned short* __restrict__ A2,
                                               const unsigned short* __restrict__ y1pb,
                                               float* __restrict__ out) {
    int nb = blockIdx.x, mb = blockIdx.y, p = blockIdx.z;
    int ph = p >> 1, pw = p & 1;
    int t = threadIdx.x;
    int lane = t & 63, wid = t >> 6;
    int wm = wid >> 1, wn = wid & 1;
    __shared__ __align__(16) unsigned short As[128 * 32];
    __shared__ __align__(16) unsigned short Bs[128 * 32];
    int m0 = mb * 128, n0 = nb * 128;
    int b = n0 >> 10, pos0 = n0 & 1023, oh0 = pos0 >> 5;
    float4v acc[4][4];
    float4v z = {0.f, 0.f, 0.f, 0.f};
#pragma unroll
    for (int i = 0; i < 4; ++i)
#pragma unroll
        for (int j = 0; j < 4; ++j) acc[i][j] = z;
    int rQ = lane >> 2, qA = lane & 3;
    const unsigned short* gA0 = A2 + (size_t)(p * 256 + m0 + wid * 32 + rQ) * 1024 + qA * 8;
    const unsigned short* gA1 = gA0 + (size_t)16 * 1024;
    unsigned short* lA0 = As + wid * 32 * 32;
    unsigned short* lA1 = As + (wid * 32 + 16) * 32;
    int n_s = t & 31, cq = t >> 5;
    int g = lane >> 4, l15 = lane & 15;
    const int plane = 34 * 34;
    for (int s = 0; s < 32; ++s) {
        int tap = s >> 3, ci0 = (s & 7) * 32;
        int ty = tap >> 1, tx = tap & 1;
        int dy = ph ? (1 - ty) : (-ty);
        int dx = pw ? (1 - tx) : (-tx);
        __syncthreads();
        stage1k(gA0 + s * 32, lA0);
        stage1k(gA1 + s * 32, lA1);
        const unsigned short* srcbase = y1pb + (size_t)(b * 256 + ci0 + cq * 4) * plane;
        int iw1 = n_s + dx + 1;
#pragma unroll
        for (int pass = 0; pass < 4; ++pass) {
            int n_l = n_s + pass * 32;
            int ih1 = oh0 + pass + dy + 1;
            const unsigned short* sp = srcbase + ih1 * 34 + iw1;
            unsigned int v0 = sp[0];
            unsigned int v1 = sp[plane];
            unsigned int v2 = sp[2 * plane];
            unsigned int v3 = sp[3 * plane];
            uint2 pk;
            pk.x = v0 | (v1 << 16);
            pk.y = v2 | (v3 << 16);
            int boff = ((n_l * 64) + cq * 8) ^ ((n_l & 3) << 4);
            *(uint2*)((char*)Bs + boff) = pk;
        }
        __syncthreads();
        short8v a[4], bb[4];
#pragma unroll
        for (int mi = 0; mi < 4; ++mi)
            a[mi] = *(const short8v*)((const char*)As + ((wm * 64 + mi * 16 + l15) * 64 + g * 16));
#pragma unroll
        for (int ni = 0; ni < 4; ++ni) {
            int nr = wn * 64 + ni * 16 + l15;
            int rb = (nr * 64 + g * 16) ^ ((nr & 3) << 4);
            bb[ni] = *(const short8v*)((const char*)Bs + rb);
        }
#pragma unroll
        for (int mi = 0; mi < 4; ++mi)
#pragma unroll
            for (int ni = 0; ni < 4; ++ni)
                acc[mi][ni] = __builtin_amdgcn_mfma_f32_16x16x32_bf16(a[mi], bb[ni], acc[mi][ni], 0, 0, 0);
    }
#pragma unroll
    for (int mi = 0; mi < 4; ++mi) {
#pragma unroll
        for (int r = 0; r < 4; ++r) {
            int co = m0 + wm * 64 + mi * 16 + g * 4 + r;
            float* dst = out + (size_t)(b * 256 + co) * 4096;
#pragma unroll
            for (int ni = 0; ni < 4; ++ni) {
                int nn = wn * 64 + ni * 16 + l15;
                int pos = pos0 + nn;
                int ohp = pos >> 5, owp = pos & 31;
                dst[(2 * ohp + ph) * 64 + 2 * owp + pw] = acc[mi][ni][r];
            }
        }
    }
}

// ---------------- BatchNorm stats (biased var) ----------------
__global__ __launch_bounds__(256) void k_bnstats(const float* __restrict__ src, int nb, int hw,
                                                 float* __restrict__ mean, float* __restrict__ rstd) {
    int ch = blockIdx.x;
    int t = threadIdx.x;
    float s = 0.f, s2 = 0.f;
    for (int b = 0; b < nb; ++b) {
        const float* p = src + ((size_t)(b * 256 + ch)) * hw;
        for (int i = t; i < hw; i += 256) {
            float v = p[i];
            s += v;
            s2 += v * v;
        }
    }
    __shared__ float rs[256], rs2[256];
    rs[t] = s; rs2[t] = s2;
    __syncthreads();
    for (int d = 128; d > 0; d >>= 1) {
        if (t < d) { rs[t] += rs[t + d]; rs2[t] += rs2[t + d]; }
        __syncthreads();
    }
    if (t == 0) {
        float n = (float)nb * (float)hw;
        float m = rs[0] / n;
        float var = rs2[0] / n - m * m;
        mean[ch] = m;
        rstd[ch] = rsqrtf(var + 1e-5f);
    }
}

// ---------------- BN+SiLU on y1 -> padded bf16 (zero halo) ----------------
__global__ __launch_bounds__(256) void k_bnsilu_pad(const float* __restrict__ y1,
                                                    const float* __restrict__ mean,
                                                    const float* __restrict__ rstd,
                                                    const float* __restrict__ gamma,
                                                    const float* __restrict__ beta,
                                                    unsigned short* __restrict__ y1pb) {
    unsigned int i = blockIdx.x * 256 + threadIdx.x;
    if (i >= 16u * 256u * 1156u) return;
    unsigned int px = i % 34u;
    unsigned int rest = i / 34u;
    unsigned int py = rest % 34u;
    unsigned int bc = rest / 34u;
    int ch = bc & 255;
    unsigned short o = 0;
    if (py >= 1 && py <= 32 && px >= 1 && px <= 32) {
        float v = y1[(size_t)bc * 1024 + (py - 1) * 32 + (px - 1)];
        float yv = gamma[ch] * (v - mean[ch]) * rstd[ch] + beta[ch];
        yv = yv / (1.f + expf(-yv));
        o = f2bf(yv);
    }
    y1pb[i] = o;
}

// ---------------- BN normalize + SiLU, in place (pow2 hw) ----------------
__global__ __launch_bounds__(256) void k_bnsilu(float* __restrict__ data,
                                                const float* __restrict__ mean,
                                                const float* __restrict__ rstd,
                                                const float* __restrict__ gamma,
                                                const float* __restrict__ beta,
                                                int shift, unsigned int total) {
    unsigned int i = blockIdx.x * 256 + threadIdx.x;
    if (i < total) {
        int ch = (int)((i >> shift) & 255u);
        float v = data[i];
        float y = gamma[ch] * (v - mean[ch]) * rstd[ch] + beta[ch];
        data[i] = y / (1.f + expf(-y));
    }
}

extern "C" void kernel_launch(void* const* d_in, const int* in_sizes, int n_in,
                              void* d_out, int out_size, void* d_ws, size_t ws_size,
                              hipStream_t stream) {
    const float* x      = (const float*)d_in[0];
    const float* w_off  = (const float*)d_in[1];
    const float* b_off  = (const float*)d_in[2];
    const float* w_def  = (const float*)d_in[3];
    const float* b_def  = (const float*)d_in[4];
    const float* gamma1 = (const float*)d_in[5];
    const float* beta1  = (const float*)d_in[6];
    const float* w_dc   = (const float*)d_in[7];
    const float* gamma2 = (const float*)d_in[8];
    const float* beta2  = (const float*)d_in[9];
    float* out = (float*)d_out;

    char* base = (char*)d_ws;
    unsigned short* S    = (unsigned short*)base;                 // 75,497,472 B
    float*          y1   = (float*)(base + 75497472);             // 16,777,216 B
    unsigned short* y1pb = (unsigned short*)(base + 92274688);    //  9,469,952 B
    unsigned short* A1   = (unsigned short*)(base + 101744640);   //  1,179,648 B
    unsigned short* A2   = (unsigned short*)(base + 102924288);   //  2,097,152 B
    float*          off  = (float*)(base + 105021440);            //  1,179,648 B
    float*          stats = (float*)(base + 106201088);           //  1,024 B
    float* mean1 = stats, *rstd1 = stats + 256, *mean2 = stats + 512, *rstd2 = stats + 768;

    k_prep_a1<<<2304, 256, 0, stream>>>(w_def, A1);
    k_prep_a2<<<4096, 256, 0, stream>>>(w_dc, A2);
    k_offset_conv<<<dim3(32, 16), 576, 0, stream>>>(x, w_off, b_off, off);
    k_sample<<<dim3(16, 16), 512, 0, stream>>>(x, off, S);
    k_gemm1<<<dim3(256, 2), 256, 0, stream>>>(A1, S, b_def, y1);
    k_bnstats<<<256, 256, 0, stream>>>(y1, 16, 1024, mean1, rstd1);
    k_bnsilu_pad<<<18497, 256, 0, stream>>>(y1, mean1, rstd1, gamma1, beta1, y1pb);
    k_gemm2<<<dim3(128, 2, 4), 256, 0, stream>>>(A2, y1pb, out);
    k_bnstats<<<256, 256, 0, stream>>>(out, 16, 4096, mean2, rstd2);
    k_bnsilu<<<65536, 256, 0, stream>>>(out, mean2, rstd2, gamma2, beta2, 12, 16777216u);
}

// Round 3
// 422.230 us; speedup vs baseline: 3.4417x; 1.3674x over previous
//
#include <hip/hip_runtime.h>
#include <math.h>

#ifdef __has_builtin
#if __has_builtin(__builtin_amdgcn_global_load_lds)
#define HAS_GLL 1
#endif
#endif
#ifndef HAS_GLL
#define HAS_GLL 0
#endif

typedef __attribute__((ext_vector_type(8))) short short8v;
typedef __attribute__((ext_vector_type(4))) float float4v;

__device__ __forceinline__ unsigned short f2bf(float f) {
    unsigned int u = __float_as_uint(f);
    u += 0x7fffu + ((u >> 16) & 1u);
    return (unsigned short)(u >> 16);
}

// wave stages 1KB into LDS: lane i -> ldsbase + 16*i, from per-lane gsrc (16B each)
__device__ __forceinline__ void stage1k(const void* gsrc, void* ldsbase) {
#if HAS_GLL
    __builtin_amdgcn_global_load_lds((const __attribute__((address_space(1))) unsigned int*)gsrc,
                                     (__attribute__((address_space(3))) unsigned int*)ldsbase,
                                     16, 0, 0);
#else
    int lane = threadIdx.x & 63;
    *(float4*)((char*)ldsbase + lane * 16) = *(const float4*)gsrc;
#endif
}

// ---------------- offset conv: 3x3, pad 1, C=256 -> 18 (fp32, LDS-staged weights) ----------------
// grid (16 hpair, 16 b), 576 threads: t = oc*32 + hh*16 + wp ; outputs (h0+hh, 2wp..2wp+1)
__global__ __launch_bounds__(576) void k_offset_conv(const float* __restrict__ x,
                                                     const float* __restrict__ w_off,
                                                     const float* __restrict__ b_off,
                                                     float* __restrict__ off) {
    int hp = blockIdx.x, b = blockIdx.y;
    int h0 = hp * 2;
    int t = threadIdx.x;
    int oc = t >> 5;
    int rem = t & 31;
    int hh = rem >> 4;
    int wp = rem & 15;
    __shared__ __align__(16) float xl[16 * 4 * 36];   // [ci][r=h0-1+r][col=xcol+1]
    __shared__ __align__(16) float wl[16 * 18 * 12];  // [ci][oc][k pad 12]
    float acc0 = 0.f, acc1 = 0.f;
    for (int cc = 0; cc < 256; cc += 16) {
        __syncthreads();
        for (int idx = t; idx < 2304; idx += 576) {
            int c_l = idx / 144;
            int r36 = idx - c_l * 144;
            int r = r36 / 36;
            int col = r36 - r * 36;
            int hy = h0 - 1 + r;
            int wx = col - 1;
            float v = 0.f;
            if (hy >= 0 && hy < 32 && wx >= 0 && wx < 32)
                v = x[(size_t)((b * 256 + cc + c_l) * 32 + hy) * 32 + wx];
            xl[c_l * 144 + r * 36 + col] = v;
        }
        for (int idx = t; idx < 2592; idx += 576) {
            int ocw = idx / 144;
            int j = idx - ocw * 144;
            int ci = j / 9;
            int k = j - ci * 9;
            wl[ci * 216 + ocw * 12 + k] = w_off[(size_t)ocw * 2304 + cc * 9 + j];
        }
        __syncthreads();
#pragma unroll 4
        for (int ci = 0; ci < 16; ++ci) {
            const float* wb = &wl[ci * 216 + oc * 12];
            float4 wA = *(const float4*)wb;
            float4 wB = *(const float4*)(wb + 4);
            float w8 = wb[8];
            const float* xb = &xl[ci * 144 + hh * 36 + 2 * wp];
            float2 r0lo = *(const float2*)(xb);
            float2 r0hi = *(const float2*)(xb + 2);
            float2 r1lo = *(const float2*)(xb + 36);
            float2 r1hi = *(const float2*)(xb + 38);
            float2 r2lo = *(const float2*)(xb + 72);
            float2 r2hi = *(const float2*)(xb + 74);
            acc0 += r0lo.x * wA.x + r0lo.y * wA.y + r0hi.x * wA.z
                  + r1lo.x * wA.w + r1lo.y * wB.x + r1hi.x * wB.y
                  + r2lo.x * wB.z + r2lo.y * wB.w + r2hi.x * w8;
            acc1 += r0lo.y * wA.x + r0hi.x * wA.y + r0hi.y * wA.z
                  + r1lo.y * wA.w + r1hi.x * wB.x + r1hi.y * wB.y
                  + r2lo.y * wB.z + r2hi.x * wB.w + r2hi.y * w8;
        }
    }
    float bo = b_off[oc];
    int h = h0 + hh;
    float2 o2;
    o2.x = acc0 + bo;
    o2.y = acc1 + bo;
    *(float2*)&off[((size_t)(b * 18 + oc) * 32 + h) * 32 + 2 * wp] = o2;
}

// ---------------- weight preps (fp32 -> bf16) ----------------
__global__ void k_prep_a1(const float* __restrict__ w_def, unsigned short* __restrict__ A1) {
    int i = blockIdx.x * 256 + threadIdx.x;  // 589824
    A1[i] = f2bf(w_def[i]);
}

__global__ void k_prep_a2(const float* __restrict__ w_dc, unsigned short* __restrict__ A2) {
    int i = blockIdx.x * 256 + threadIdx.x;  // 1048576
    int ci = i & 255;
    int tq = (i >> 8) & 3;
    int co = (i >> 10) & 255;
    int p  = i >> 18;
    int ph = p >> 1, pw = p & 1;
    int ty = tq >> 1, tx = tq & 1;
    int kh = 2 * ty + 1 - ph;
    int kw = 2 * tx + 1 - pw;
    A2[i] = f2bf(w_dc[((ci * 256 + co) * 4 + kh) * 4 + kw]);
}

// ---------------- bilinear sampler: S[n][c*9+k] bf16, bank-conflict-free staging ----------------
// grid (16 tiles, 16 b, 2 cgroups), 512 threads
__global__ __launch_bounds__(512) void k_sample(const float* __restrict__ x,
                                                const float* __restrict__ off,
                                                unsigned short* __restrict__ S) {
    int tile = blockIdx.x, b = blockIdx.y, cg = blockIdx.z;
    int t = threadIdx.x;
    int h0 = tile * 2;
    int n0 = b * 1024 + tile * 64;
    int cbase = cg * 128;
    __shared__ int   my0[576];
    __shared__ int   mx0[576];
    __shared__ float mwy[576];
    __shared__ float mwx[576];
    __shared__ __align__(16) float xpl[8 * 1156];  // ch stride 1156 (+4 banks), row stride 36 (+4 banks)
    __shared__ __align__(16) unsigned short sS[64 * 72];

    for (int idx = t; idx < 576; idx += 512) {
        int k = idx >> 6, pos = idx & 63;
        int h = h0 + (pos >> 5), w = pos & 31;
        float dy = off[((b * 18 + 2 * k) * 32 + h) * 32 + w];
        float dx = off[((b * 18 + 2 * k + 1) * 32 + h) * 32 + w];
        float py = (float)(h + (k / 3) - 1) + dy;
        float px = (float)(w + (k % 3) - 1) + dx;
        float fy = floorf(py), fx = floorf(px);
        my0[idx] = (int)fy;
        mx0[idx] = (int)fx;
        mwy[idx] = py - fy;
        mwx[idx] = px - fx;
    }

    for (int cc = cbase; cc < cbase + 128; cc += 8) {
        __syncthreads();
        for (int idx = t; idx < 2048; idx += 512) {
            int c_l = idx >> 8, r = (idx >> 3) & 31, x4 = (idx & 7) << 2;
            *(float4*)&xpl[c_l * 1156 + r * 36 + x4] =
                *(const float4*)&x[(size_t)((b * 256 + cc + c_l) * 32 + r) * 32 + x4];
        }
        __syncthreads();
        for (int idx = t; idx < 4608; idx += 512) {
            int pos = idx / 72;
            int kc = idx - pos * 72;
            int c_l = kc / 9;
            int k = kc - c_l * 9;
            int m = (k << 6) + pos;
            int y0 = my0[m], x0 = mx0[m];
            float wy = mwy[m], wx = mwx[m];
            const float* pl = xpl + c_l * 1156;
            float v = 0.f;
            bool ya = (y0 >= 0) && (y0 < 32);
            bool yb = (y0 >= -1) && (y0 < 31);
            bool xa = (x0 >= 0) && (x0 < 32);
            bool xb = (x0 >= -1) && (x0 < 31);
            if (ya && xa) v += (1.f - wy) * (1.f - wx) * pl[y0 * 36 + x0];
            if (ya && xb) v += (1.f - wy) * wx         * pl[y0 * 36 + x0 + 1];
            if (yb && xa) v += wy * (1.f - wx)         * pl[(y0 + 1) * 36 + x0];
            if (yb && xb) v += wy * wx                  * pl[(y0 + 1) * 36 + x0 + 1];
            sS[pos * 72 + kc] = f2bf(v);
        }
        __syncthreads();
        for (int idx = t; idx < 576; idx += 512) {
            int row = idx / 9, ch = idx - row * 9;
            float4 vv = *(const float4*)((const char*)sS + row * 144 + ch * 16);
            *(float4*)(S + (size_t)(n0 + row) * 2304 + cc * 9 + ch * 8) = vv;
        }
    }
}

// ---------------- GEMM1: y1[co][n] = sum_K A1[co][K] * S[n][K], K=2304 ----------------
__global__ __launch_bounds__(256) void k_gemm1(const unsigned short* __restrict__ A1,
                                               const unsigned short* __restrict__ S,
                                               const float* __restrict__ b_def,
                                               float* __restrict__ y1) {
    int nb = blockIdx.x, mb = blockIdx.y;
    int t = threadIdx.x;
    int lane = t & 63, wid = t >> 6;
    int wm = wid >> 1, wn = wid & 1;
    __shared__ __align__(16) unsigned short As[128 * 32];
    __shared__ __align__(16) unsigned short Bs[64 * 32];
    int m0 = mb * 128, n0 = nb * 64;
    float4v acc[4][2];
    float4v z = {0.f, 0.f, 0.f, 0.f};
#pragma unroll
    for (int i = 0; i < 4; ++i) { acc[i][0] = z; acc[i][1] = z; }
    int rQ = lane >> 2, qA = lane & 3;
    const unsigned short* gA0 = A1 + (size_t)(m0 + wid * 32 + rQ) * 2304 + qA * 8;
    const unsigned short* gA1 = gA0 + (size_t)16 * 2304;
    const unsigned short* gB0 = S + (size_t)(n0 + wid * 16 + rQ) * 2304 + qA * 8;
    unsigned short* lA0 = As + wid * 32 * 32;
    unsigned short* lA1 = As + (wid * 32 + 16) * 32;
    unsigned short* lB0 = Bs + wid * 16 * 32;
    int g = lane >> 4, l15 = lane & 15;
    for (int s = 0; s < 72; ++s) {
        __syncthreads();
        stage1k(gA0 + s * 32, lA0);
        stage1k(gA1 + s * 32, lA1);
        stage1k(gB0 + s * 32, lB0);
        __syncthreads();
        short8v a[4], bb[2];
#pragma unroll
        for (int mi = 0; mi < 4; ++mi)
            a[mi] = *(const short8v*)((const char*)As + ((wm * 64 + mi * 16 + l15) * 64 + g * 16));
#pragma unroll
        for (int ni = 0; ni < 2; ++ni)
            bb[ni] = *(const short8v*)((const char*)Bs + ((wn * 32 + ni * 16 + l15) * 64 + g * 16));
#pragma unroll
        for (int mi = 0; mi < 4; ++mi)
#pragma unroll
            for (int ni = 0; ni < 2; ++ni)
                acc[mi][ni] = __builtin_amdgcn_mfma_f32_16x16x32_bf16(a[mi], bb[ni], acc[mi][ni], 0, 0, 0);
    }
    int b = n0 >> 10;
    int posb = n0 & 1023;
#pragma unroll
    for (int mi = 0; mi < 4; ++mi) {
#pragma unroll
        for (int r = 0; r < 4; ++r) {
            int co = m0 + wm * 64 + mi * 16 + g * 4 + r;
            float bv = b_def[co];
            float* dst = y1 + ((size_t)(b * 256 + co) << 10) + posb;
#pragma unroll
            for (int ni = 0; ni < 2; ++ni)
                dst[wn * 32 + ni * 16 + l15] = acc[mi][ni][r] + bv;
        }
    }
}

// ---------------- GEMM2: convT by parity ----------------
__global__ __launch_bounds__(256) void k_gemm2(const unsigned short* __restrict__ A2,
                                               const unsigned short* __restrict__ y1pb,
                                               float* __restrict__ out) {
    int nb = blockIdx.x, mb = blockIdx.y, p = blockIdx.z;
    int ph = p >> 1, pw = p & 1;
    int t = threadIdx.x;
    int lane = t & 63, wid = t >> 6;
    int wm = wid >> 1, wn = wid & 1;
    __shared__ __align__(16) unsigned short As[128 * 32];
    __shared__ __align__(16) unsigned short Bs[128 * 32];
    int m0 = mb * 128, n0 = nb * 128;
    int b = n0 >> 10, pos0 = n0 & 1023, oh0 = pos0 >> 5;
    float4v acc[4][4];
    float4v z = {0.f, 0.f, 0.f, 0.f};
#pragma unroll
    for (int i = 0; i < 4; ++i)
#pragma unroll
        for (int j = 0; j < 4; ++j) acc[i][j] = z;
    int rQ = lane >> 2, qA = lane & 3;
    const unsigned short* gA0 = A2 + (size_t)(p * 256 + m0 + wid * 32 + rQ) * 1024 + qA * 8;
    const unsigned short* gA1 = gA0 + (size_t)16 * 1024;
    unsigned short* lA0 = As + wid * 32 * 32;
    unsigned short* lA1 = As + (wid * 32 + 16) * 32;
    int n_s = t & 31, cq = t >> 5;
    int g = lane >> 4, l15 = lane & 15;
    const int plane = 34 * 34;
    for (int s = 0; s < 32; ++s) {
        int tap = s >> 3, ci0 = (s & 7) * 32;
        int ty = tap >> 1, tx = tap & 1;
        int dy = ph ? (1 - ty) : (-ty);
        int dx = pw ? (1 - tx) : (-tx);
        __syncthreads();
        stage1k(gA0 + s * 32, lA0);
        stage1k(gA1 + s * 32, lA1);
        const unsigned short* srcbase = y1pb + (size_t)(b * 256 + ci0 + cq * 4) * plane;
        int iw1 = n_s + dx + 1;
#pragma unroll
        for (int pass = 0; pass < 4; ++pass) {
            int n_l = n_s + pass * 32;
            int ih1 = oh0 + pass + dy + 1;
            const unsigned short* sp = srcbase + ih1 * 34 + iw1;
            unsigned int v0 = sp[0];
            unsigned int v1 = sp[plane];
            unsigned int v2 = sp[2 * plane];
            unsigned int v3 = sp[3 * plane];
            uint2 pk;
            pk.x = v0 | (v1 << 16);
            pk.y = v2 | (v3 << 16);
            int boff = ((n_l * 64) + cq * 8) ^ ((n_l & 3) << 4);
            *(uint2*)((char*)Bs + boff) = pk;
        }
        __syncthreads();
        short8v a[4], bb[4];
#pragma unroll
        for (int mi = 0; mi < 4; ++mi)
            a[mi] = *(const short8v*)((const char*)As + ((wm * 64 + mi * 16 + l15) * 64 + g * 16));
#pragma unroll
        for (int ni = 0; ni < 4; ++ni) {
            int nr = wn * 64 + ni * 16 + l15;
            int rb = (nr * 64 + g * 16) ^ ((nr & 3) << 4);
            bb[ni] = *(const short8v*)((const char*)Bs + rb);
        }
#pragma unroll
        for (int mi = 0; mi < 4; ++mi)
#pragma unroll
            for (int ni = 0; ni < 4; ++ni)
                acc[mi][ni] = __builtin_amdgcn_mfma_f32_16x16x32_bf16(a[mi], bb[ni], acc[mi][ni], 0, 0, 0);
    }
#pragma unroll
    for (int mi = 0; mi < 4; ++mi) {
#pragma unroll
        for (int r = 0; r < 4; ++r) {
            int co = m0 + wm * 64 + mi * 16 + g * 4 + r;
            float* dst = out + (size_t)(b * 256 + co) * 4096;
#pragma unroll
            for (int ni = 0; ni < 4; ++ni) {
                int nn = wn * 64 + ni * 16 + l15;
                int pos = pos0 + nn;
                int ohp = pos >> 5, owp = pos & 31;
                dst[(2 * ohp + ph) * 64 + 2 * owp + pw] = acc[mi][ni][r];
            }
        }
    }
}

// ---------------- BN stats: per-(ch,b) partials, then finisher ----------------
__global__ __launch_bounds__(256) void k_bnstats_part(const float* __restrict__ src, int hw,
                                                      float* __restrict__ pstats) {
    int ch = blockIdx.x, b = blockIdx.y;
    int t = threadIdx.x;
    const float* p = src + ((size_t)(b * 256 + ch)) * hw;
    float s = 0.f, s2 = 0.f;
    for (int i = t * 4; i < hw; i += 1024) {
        float4 v = *(const float4*)&p[i];
        s  += v.x + v.y + v.z + v.w;
        s2 += v.x * v.x + v.y * v.y + v.z * v.z + v.w * v.w;
    }
    __shared__ float rs[256], rs2[256];
    rs[t] = s; rs2[t] = s2;
    __syncthreads();
    for (int d = 128; d > 0; d >>= 1) {
        if (t < d) { rs[t] += rs[t + d]; rs2[t] += rs2[t + d]; }
        __syncthreads();
    }
    if (t == 0) {
        pstats[ch * 16 + b] = rs[0];
        pstats[4096 + ch * 16 + b] = rs2[0];
    }
}

__global__ __launch_bounds__(256) void k_bnfin(const float* __restrict__ pstats, float n,
                                               float* __restrict__ mean, float* __restrict__ rstd) {
    int ch = threadIdx.x;
    float s = 0.f, s2 = 0.f;
    for (int b = 0; b < 16; ++b) {
        s += pstats[ch * 16 + b];
        s2 += pstats[4096 + ch * 16 + b];
    }
    float m = s / n;
    float var = s2 / n - m * m;
    mean[ch] = m;
    rstd[ch] = rsqrtf(var + 1e-5f);
}

// ---------------- BN+SiLU on y1 -> padded bf16 (zero halo) ----------------
__global__ __launch_bounds__(256) void k_bnsilu_pad(const float* __restrict__ y1,
                                                    const float* __restrict__ mean,
                                                    const float* __restrict__ rstd,
                                                    const float* __restrict__ gamma,
                                                    const float* __restrict__ beta,
                                                    unsigned short* __restrict__ y1pb) {
    unsigned int i = blockIdx.x * 256 + threadIdx.x;
    if (i >= 16u * 256u * 1156u) return;
    unsigned int px = i % 34u;
    unsigned int rest = i / 34u;
    unsigned int py = rest % 34u;
    unsigned int bc = rest / 34u;
    int ch = bc & 255;
    unsigned short o = 0;
    if (py >= 1 && py <= 32 && px >= 1 && px <= 32) {
        float v = y1[(size_t)bc * 1024 + (py - 1) * 32 + (px - 1)];
        float yv = gamma[ch] * (v - mean[ch]) * rstd[ch] + beta[ch];
        yv = yv / (1.f + expf(-yv));
        o = f2bf(yv);
    }
    y1pb[i] = o;
}

// ---------------- final BN+SiLU on out, float4 vectorized ----------------
__global__ __launch_bounds__(256) void k_bnsilu4(float* __restrict__ data,
                                                 const float* __restrict__ mean,
                                                 const float* __restrict__ rstd,
                                                 const float* __restrict__ gamma,
                                                 const float* __restrict__ beta) {
    unsigned int i = blockIdx.x * 256 + threadIdx.x;  // float4 index, 4194304 total
    int ch = (int)((i >> 10) & 255u);
    float m = mean[ch], rs = rstd[ch], g = gamma[ch], bt = beta[ch];
    float4 v = ((float4*)data)[i];
    float y0 = g * (v.x - m) * rs + bt;
    float y1 = g * (v.y - m) * rs + bt;
    float y2 = g * (v.z - m) * rs + bt;
    float y3 = g * (v.w - m) * rs + bt;
    v.x = y0 / (1.f + expf(-y0));
    v.y = y1 / (1.f + expf(-y1));
    v.z = y2 / (1.f + expf(-y2));
    v.w = y3 / (1.f + expf(-y3));
    ((float4*)data)[i] = v;
}

extern "C" void kernel_launch(void* const* d_in, const int* in_sizes, int n_in,
                              void* d_out, int out_size, void* d_ws, size_t ws_size,
                              hipStream_t stream) {
    const float* x      = (const float*)d_in[0];
    const float* w_off  = (const float*)d_in[1];
    const float* b_off  = (const float*)d_in[2];
    const float* w_def  = (const float*)d_in[3];
    const float* b_def  = (const float*)d_in[4];
    const float* gamma1 = (const float*)d_in[5];
    const float* beta1  = (const float*)d_in[6];
    const float* w_dc   = (const float*)d_in[7];
    const float* gamma2 = (const float*)d_in[8];
    const float* beta2  = (const float*)d_in[9];
    float* out = (float*)d_out;

    char* base = (char*)d_ws;
    unsigned short* S    = (unsigned short*)base;                 // 75,497,472 B
    float*          y1   = (float*)(base + 75497472);             // 16,777,216 B
    unsigned short* y1pb = (unsigned short*)(base + 92274688);    //  9,469,952 B
    unsigned short* A1   = (unsigned short*)(base + 101744640);   //  1,179,648 B
    unsigned short* A2   = (unsigned short*)(base + 102924288);   //  2,097,152 B
    float*          off  = (float*)(base + 105021440);            //  1,179,648 B
    float*          stats = (float*)(base + 106201088);           //  1,024 B
    float* mean1 = stats, *rstd1 = stats + 256, *mean2 = stats + 512, *rstd2 = stats + 768;
    float* pstats = off;  // off is dead after k_sample; reuse for BN partials (32 KB)

    k_prep_a1<<<2304, 256, 0, stream>>>(w_def, A1);
    k_prep_a2<<<4096, 256, 0, stream>>>(w_dc, A2);
    k_offset_conv<<<dim3(16, 16), 576, 0, stream>>>(x, w_off, b_off, off);
    k_sample<<<dim3(16, 16, 2), 512, 0, stream>>>(x, off, S);
    k_gemm1<<<dim3(256, 2), 256, 0, stream>>>(A1, S, b_def, y1);
    k_bnstats_part<<<dim3(256, 16), 256, 0, stream>>>(y1, 1024, pstats);
    k_bnfin<<<1, 256, 0, stream>>>(pstats, 16384.f, mean1, rstd1);
    k_bnsilu_pad<<<18497, 256, 0, stream>>>(y1, mean1, rstd1, gamma1, beta1, y1pb);
    k_gemm2<<<dim3(128, 2, 4), 256, 0, stream>>>(A2, y1pb, out);
    k_bnstats_part<<<dim3(256, 16), 256, 0, stream>>>(out, 4096, pstats);
    k_bnfin<<<1, 256, 0, stream>>>(pstats, 65536.f, mean2, rstd2);
    k_bnsilu4<<<16384, 256, 0, stream>>>(out, mean2, rstd2, gamma2, beta2);
}

// Round 4
// 352.882 us; speedup vs baseline: 4.1181x; 1.1965x over previous
//
#include <hip/hip_runtime.h>
#include <math.h>

#ifdef __has_builtin
#if __has_builtin(__builtin_amdgcn_global_load_lds)
#define HAS_GLL 1
#endif
#endif
#ifndef HAS_GLL
#define HAS_GLL 0
#endif

typedef __attribute__((ext_vector_type(8))) short short8v;
typedef __attribute__((ext_vector_type(4))) float float4v;

__device__ __forceinline__ unsigned short f2bf(float f) {
    unsigned int u = __float_as_uint(f);
    u += 0x7fffu + ((u >> 16) & 1u);
    return (unsigned short)(u >> 16);
}

// wave stages 1KB into LDS: lane i -> ldsbase + 16*i, from per-lane gsrc (16B each)
__device__ __forceinline__ void stage1k(const void* gsrc, void* ldsbase) {
#if HAS_GLL
    __builtin_amdgcn_global_load_lds((const __attribute__((address_space(1))) unsigned int*)gsrc,
                                     (__attribute__((address_space(3))) unsigned int*)ldsbase,
                                     16, 0, 0);
#else
    int lane = threadIdx.x & 63;
    *(float4*)((char*)ldsbase + lane * 16) = *(const float4*)gsrc;
#endif
}

// ---------------- offset conv: 3x3, pad 1, C=256 -> 18 (fp32, LDS-staged weights) ----------------
__global__ __launch_bounds__(576) void k_offset_conv(const float* __restrict__ x,
                                                     const float* __restrict__ w_off,
                                                     const float* __restrict__ b_off,
                                                     float* __restrict__ off) {
    int hp = blockIdx.x, b = blockIdx.y;
    int h0 = hp * 2;
    int t = threadIdx.x;
    int oc = t >> 5;
    int rem = t & 31;
    int hh = rem >> 4;
    int wp = rem & 15;
    __shared__ __align__(16) float xl[16 * 4 * 36];   // [ci][r][col]
    __shared__ __align__(16) float wl[16 * 18 * 12];  // [ci][oc][k pad 12]
    float acc0 = 0.f, acc1 = 0.f;
    for (int cc = 0; cc < 256; cc += 16) {
        __syncthreads();
        for (int idx = t; idx < 2304; idx += 576) {
            int c_l = idx / 144;
            int r36 = idx - c_l * 144;
            int r = r36 / 36;
            int col = r36 - r * 36;
            int hy = h0 - 1 + r;
            int wx = col - 1;
            float v = 0.f;
            if (hy >= 0 && hy < 32 && wx >= 0 && wx < 32)
                v = x[(size_t)((b * 256 + cc + c_l) * 32 + hy) * 32 + wx];
            xl[c_l * 144 + r * 36 + col] = v;
        }
        for (int idx = t; idx < 2592; idx += 576) {
            int ocw = idx / 144;
            int j = idx - ocw * 144;
            int ci = j / 9;
            int k = j - ci * 9;
            wl[ci * 216 + ocw * 12 + k] = w_off[(size_t)ocw * 2304 + cc * 9 + j];
        }
        __syncthreads();
#pragma unroll 4
        for (int ci = 0; ci < 16; ++ci) {
            const float* wb = &wl[ci * 216 + oc * 12];
            float4 wA = *(const float4*)wb;
            float4 wB = *(const float4*)(wb + 4);
            float w8 = wb[8];
            const float* xb = &xl[ci * 144 + hh * 36 + 2 * wp];
            float2 r0lo = *(const float2*)(xb);
            float2 r0hi = *(const float2*)(xb + 2);
            float2 r1lo = *(const float2*)(xb + 36);
            float2 r1hi = *(const float2*)(xb + 38);
            float2 r2lo = *(const float2*)(xb + 72);
            float2 r2hi = *(const float2*)(xb + 74);
            acc0 += r0lo.x * wA.x + r0lo.y * wA.y + r0hi.x * wA.z
                  + r1lo.x * wA.w + r1lo.y * wB.x + r1hi.x * wB.y
                  + r2lo.x * wB.z + r2lo.y * wB.w + r2hi.x * w8;
            acc1 += r0lo.y * wA.x + r0hi.x * wA.y + r0hi.y * wA.z
                  + r1lo.y * wA.w + r1hi.x * wB.x + r1hi.y * wB.y
                  + r2lo.y * wB.z + r2hi.x * wB.w + r2hi.y * w8;
        }
    }
    float bo = b_off[oc];
    int h = h0 + hh;
    float2 o2;
    o2.x = acc0 + bo;
    o2.y = acc1 + bo;
    *(float2*)&off[((size_t)(b * 18 + oc) * 32 + h) * 32 + 2 * wp] = o2;
}

// ---------------- weight preps (fp32 -> bf16) ----------------
__global__ void k_prep_a1(const float* __restrict__ w_def, unsigned short* __restrict__ A1) {
    int i = blockIdx.x * 256 + threadIdx.x;  // 589824
    A1[i] = f2bf(w_def[i]);
}

__global__ void k_prep_a2(const float* __restrict__ w_dc, unsigned short* __restrict__ A2) {
    int i = blockIdx.x * 256 + threadIdx.x;  // 1048576
    int ci = i & 255;
    int tq = (i >> 8) & 3;
    int co = (i >> 10) & 255;
    int p  = i >> 18;
    int ph = p >> 1, pw = p & 1;
    int ty = tq >> 1, tx = tq & 1;
    int kh = 2 * ty + 1 - ph;
    int kw = 2 * tx + 1 - pw;
    A2[i] = f2bf(w_dc[((ci * 256 + co) * 4 + kh) * 4 + kw]);
}

// ---------------- bilinear sampler: S[n][c*9+k] bf16 ----------------
// 576 threads: t = k*64 + pos (wave = one tap). Metadata in registers; no meta LDS.
// grid (16 tiles, 16 b, 2 cgroups)
__global__ __launch_bounds__(576) void k_sample(const float* __restrict__ x,
                                                const float* __restrict__ off,
                                                unsigned short* __restrict__ S) {
    int tile = blockIdx.x, b = blockIdx.y, cg = blockIdx.z;
    int t = threadIdx.x;
    int h0 = tile * 2;
    int n0 = b * 1024 + tile * 64;
    int cbase = cg * 128;
    int k = t >> 6;                 // 0..8, one tap per wave
    int pos = t & 63;
    int h = h0 + (pos >> 5), w = pos & 31;
    __shared__ __align__(16) float xpl[8 * 1156];        // [c_l] stride 1156, row stride 36
    __shared__ __align__(16) unsigned short sS[72 * 66]; // [kc][pos pad 66]

    // per-thread bilinear metadata (registers only)
    float dy = off[(b * 18 + 2 * k) * 1024 + h * 32 + w];
    float dx = off[(b * 18 + 2 * k + 1) * 1024 + h * 32 + w];
    float py = (float)(h + (k / 3) - 1) + dy;
    float px = (float)(w + (k % 3) - 1) + dx;
    float fy = floorf(py), fx = floorf(px);
    int y0i = (int)fy, x0i = (int)fx;
    float wy = py - fy, wx = px - fx;
    float vy0 = (y0i >= 0 && y0i < 32) ? 1.f : 0.f;
    float vy1 = (y0i >= -1 && y0i < 31) ? 1.f : 0.f;
    float vx0 = (x0i >= 0 && x0i < 32) ? 1.f : 0.f;
    float vx1 = (x0i >= -1 && x0i < 31) ? 1.f : 0.f;
    int y0c = min(max(y0i, 0), 31), y1c = min(max(y0i + 1, 0), 31);
    int x0c = min(max(x0i, 0), 31), x1c = min(max(x0i + 1, 0), 31);
    float w00 = (1.f - wy) * (1.f - wx) * vy0 * vx0;
    float w01 = (1.f - wy) * wx * vy0 * vx1;
    float w10 = wy * (1.f - wx) * vy1 * vx0;
    float w11 = wy * wx * vy1 * vx1;
    int a00 = y0c * 36 + x0c, a01 = y0c * 36 + x1c;
    int a10 = y1c * 36 + x0c, a11 = y1c * 36 + x1c;

    int wr_row = t / 9;             // 0..63
    int wr_ch  = t - wr_row * 9;    // 0..8

    for (int cc = cbase; cc < cbase + 128; cc += 8) {
        __syncthreads();
        for (int idx = t; idx < 2048; idx += 576) {
            int c_l = idx >> 8, r = (idx >> 3) & 31, x4 = (idx & 7) << 2;
            *(float4*)&xpl[c_l * 1156 + r * 36 + x4] =
                *(const float4*)&x[(size_t)((b * 256 + cc + c_l) * 32 + r) * 32 + x4];
        }
        __syncthreads();
#pragma unroll
        for (int c_l = 0; c_l < 8; ++c_l) {
            const float* pl = xpl + c_l * 1156;
            float v = w00 * pl[a00] + w01 * pl[a01] + w10 * pl[a10] + w11 * pl[a11];
            sS[(c_l * 9 + k) * 66 + pos] = f2bf(v);
        }
        __syncthreads();
        // writer: one (row, ch) per thread; 8 near-conflict-free b16 reads + 16B store
        uint4 qv;
        {
            int base = wr_ch * 8;
            unsigned int s0 = sS[(base + 0) * 66 + wr_row];
            unsigned int s1 = sS[(base + 1) * 66 + wr_row];
            unsigned int s2 = sS[(base + 2) * 66 + wr_row];
            unsigned int s3 = sS[(base + 3) * 66 + wr_row];
            unsigned int s4 = sS[(base + 4) * 66 + wr_row];
            unsigned int s5 = sS[(base + 5) * 66 + wr_row];
            unsigned int s6 = sS[(base + 6) * 66 + wr_row];
            unsigned int s7 = sS[(base + 7) * 66 + wr_row];
            qv.x = s0 | (s1 << 16);
            qv.y = s2 | (s3 << 16);
            qv.z = s4 | (s5 << 16);
            qv.w = s6 | (s7 << 16);
        }
        *(uint4*)(S + (size_t)(n0 + wr_row) * 2304 + cc * 9 + wr_ch * 8) = qv;
    }
}

// ---------------- GEMM1: y1[co][n] = sum_K A1[co][K] * S[n][K], K=2304 ----------------
__global__ __launch_bounds__(256) void k_gemm1(const unsigned short* __restrict__ A1,
                                               const unsigned short* __restrict__ S,
                                               const float* __restrict__ b_def,
                                               float* __restrict__ y1) {
    int nb = blockIdx.x, mb = blockIdx.y;
    int t = threadIdx.x;
    int lane = t & 63, wid = t >> 6;
    int wm = wid >> 1, wn = wid & 1;
    __shared__ __align__(16) unsigned short As[128 * 32];
    __shared__ __align__(16) unsigned short Bs[64 * 32];
    int m0 = mb * 128, n0 = nb * 64;
    float4v acc[4][2];
    float4v z = {0.f, 0.f, 0.f, 0.f};
#pragma unroll
    for (int i = 0; i < 4; ++i) { acc[i][0] = z; acc[i][1] = z; }
    int rQ = lane >> 2, qA = lane & 3;
    const unsigned short* gA0 = A1 + (size_t)(m0 + wid * 32 + rQ) * 2304 + qA * 8;
    const unsigned short* gA1 = gA0 + (size_t)16 * 2304;
    const unsigned short* gB0 = S + (size_t)(n0 + wid * 16 + rQ) * 2304 + qA * 8;
    unsigned short* lA0 = As + wid * 32 * 32;
    unsigned short* lA1 = As + (wid * 32 + 16) * 32;
    unsigned short* lB0 = Bs + wid * 16 * 32;
    int g = lane >> 4, l15 = lane & 15;
    for (int s = 0; s < 72; ++s) {
        __syncthreads();
        stage1k(gA0 + s * 32, lA0);
        stage1k(gA1 + s * 32, lA1);
        stage1k(gB0 + s * 32, lB0);
        __syncthreads();
        short8v a[4], bb[2];
#pragma unroll
        for (int mi = 0; mi < 4; ++mi)
            a[mi] = *(const short8v*)((const char*)As + ((wm * 64 + mi * 16 + l15) * 64 + g * 16));
#pragma unroll
        for (int ni = 0; ni < 2; ++ni)
            bb[ni] = *(const short8v*)((const char*)Bs + ((wn * 32 + ni * 16 + l15) * 64 + g * 16));
#pragma unroll
        for (int mi = 0; mi < 4; ++mi)
#pragma unroll
            for (int ni = 0; ni < 2; ++ni)
                acc[mi][ni] = __builtin_amdgcn_mfma_f32_16x16x32_bf16(a[mi], bb[ni], acc[mi][ni], 0, 0, 0);
    }
    int b = n0 >> 10;
    int posb = n0 & 1023;
#pragma unroll
    for (int mi = 0; mi < 4; ++mi) {
#pragma unroll
        for (int r = 0; r < 4; ++r) {
            int co = m0 + wm * 64 + mi * 16 + g * 4 + r;
            float bv = b_def[co];
            float* dst = y1 + ((size_t)(b * 256 + co) << 10) + posb;
#pragma unroll
            for (int ni = 0; ni < 2; ++ni)
                dst[wn * 32 + ni * 16 + l15] = acc[mi][ni][r] + bv;
        }
    }
}

// ---------------- GEMM2: convT by parity ----------------
__global__ __launch_bounds__(256) void k_gemm2(const unsigned short* __restrict__ A2,
                                               const unsigned short* __restrict__ y1pb,
                                               float* __restrict__ out) {
    int nb = blockIdx.x, mb = blockIdx.y, p = blockIdx.z;
    int ph = p >> 1, pw = p & 1;
    int t = threadIdx.x;
    int lane = t & 63, wid = t >> 6;
    int wm = wid >> 1, wn = wid & 1;
    __shared__ __align__(16) unsigned short As[128 * 32];
    __shared__ __align__(16) unsigned short Bs[128 * 32];
    int m0 = mb * 128, n0 = nb * 128;
    int b = n0 >> 10, pos0 = n0 & 1023, oh0 = pos0 >> 5;
    float4v acc[4][4];
    float4v z = {0.f, 0.f, 0.f, 0.f};
#pragma unroll
    for (int i = 0; i < 4; ++i)
#pragma unroll
        for (int j = 0; j < 4; ++j) acc[i][j] = z;
    int rQ = lane >> 2, qA = lane & 3;
    const unsigned short* gA0 = A2 + (size_t)(p * 256 + m0 + wid * 32 + rQ) * 1024 + qA * 8;
    const unsigned short* gA1 = gA0 + (size_t)16 * 1024;
    unsigned short* lA0 = As + wid * 32 * 32;
    unsigned short* lA1 = As + (wid * 32 + 16) * 32;
    int n_s = t & 31, cq = t >> 5;
    int g = lane >> 4, l15 = lane & 15;
    const int plane = 34 * 34;
    for (int s = 0; s < 32; ++s) {
        int tap = s >> 3, ci0 = (s & 7) * 32;
        int ty = tap >> 1, tx = tap & 1;
        int dy = ph ? (1 - ty) : (-ty);
        int dx = pw ? (1 - tx) : (-tx);
        __syncthreads();
        stage1k(gA0 + s * 32, lA0);
        stage1k(gA1 + s * 32, lA1);
        const unsigned short* srcbase = y1pb + (size_t)(b * 256 + ci0 + cq * 4) * plane;
        int iw1 = n_s + dx + 1;
#pragma unroll
        for (int pass = 0; pass < 4; ++pass) {
            int n_l = n_s + pass * 32;
            int ih1 = oh0 + pass + dy + 1;
            const unsigned short* sp = srcbase + ih1 * 34 + iw1;
            unsigned int v0 = sp[0];
            unsigned int v1 = sp[plane];
            unsigned int v2 = sp[2 * plane];
            unsigned int v3 = sp[3 * plane];
            uint2 pk;
            pk.x = v0 | (v1 << 16);
            pk.y = v2 | (v3 << 16);
            int boff = ((n_l * 64) + cq * 8) ^ ((n_l & 3) << 4);
            *(uint2*)((char*)Bs + boff) = pk;
        }
        __syncthreads();
        short8v a[4], bb[4];
#pragma unroll
        for (int mi = 0; mi < 4; ++mi)
            a[mi] = *(const short8v*)((const char*)As + ((wm * 64 + mi * 16 + l15) * 64 + g * 16));
#pragma unroll
        for (int ni = 0; ni < 4; ++ni) {
            int nr = wn * 64 + ni * 16 + l15;
            int rb = (nr * 64 + g * 16) ^ ((nr & 3) << 4);
            bb[ni] = *(const short8v*)((const char*)Bs + rb);
        }
#pragma unroll
        for (int mi = 0; mi < 4; ++mi)
#pragma unroll
            for (int ni = 0; ni < 4; ++ni)
                acc[mi][ni] = __builtin_amdgcn_mfma_f32_16x16x32_bf16(a[mi], bb[ni], acc[mi][ni], 0, 0, 0);
    }
#pragma unroll
    for (int mi = 0; mi < 4; ++mi) {
#pragma unroll
        for (int r = 0; r < 4; ++r) {
            int co = m0 + wm * 64 + mi * 16 + g * 4 + r;
            float* dst = out + (size_t)(b * 256 + co) * 4096;
#pragma unroll
            for (int ni = 0; ni < 4; ++ni) {
                int nn = wn * 64 + ni * 16 + l15;
                int pos = pos0 + nn;
                int ohp = pos >> 5, owp = pos & 31;
                dst[(2 * ohp + ph) * 64 + 2 * owp + pw] = acc[mi][ni][r];
            }
        }
    }
}

// ---------------- BN stats: per-(ch,b) partials, then finisher ----------------
__global__ __launch_bounds__(256) void k_bnstats_part(const float* __restrict__ src, int hw,
                                                      float* __restrict__ pstats) {
    int ch = blockIdx.x, b = blockIdx.y;
    int t = threadIdx.x;
    const float* p = src + ((size_t)(b * 256 + ch)) * hw;
    float s = 0.f, s2 = 0.f;
    for (int i = t * 4; i < hw; i += 1024) {
        float4 v = *(const float4*)&p[i];
        s  += v.x + v.y + v.z + v.w;
        s2 += v.x * v.x + v.y * v.y + v.z * v.z + v.w * v.w;
    }
    __shared__ float rs[256], rs2[256];
    rs[t] = s; rs2[t] = s2;
    __syncthreads();
    for (int d = 128; d > 0; d >>= 1) {
        if (t < d) { rs[t] += rs[t + d]; rs2[t] += rs2[t + d]; }
        __syncthreads();
    }
    if (t == 0) {
        pstats[ch * 16 + b] = rs[0];
        pstats[4096 + ch * 16 + b] = rs2[0];
    }
}

__global__ __launch_bounds__(256) void k_bnfin(const float* __restrict__ pstats, float n,
                                               float* __restrict__ mean, float* __restrict__ rstd) {
    int ch = threadIdx.x;
    float s = 0.f, s2 = 0.f;
    for (int b = 0; b < 16; ++b) {
        s += pstats[ch * 16 + b];
        s2 += pstats[4096 + ch * 16 + b];
    }
    float m = s / n;
    float var = s2 / n - m * m;
    mean[ch] = m;
    rstd[ch] = rsqrtf(var + 1e-5f);
}

// ---------------- BN+SiLU on y1 -> padded bf16 (zero halo) ----------------
__global__ __launch_bounds__(256) void k_bnsilu_pad(const float* __restrict__ y1,
                                                    const float* __restrict__ mean,
                                                    const float* __restrict__ rstd,
                                                    const float* __restrict__ gamma,
                                                    const float* __restrict__ beta,
                                                    unsigned short* __restrict__ y1pb) {
    unsigned int i = blockIdx.x * 256 + threadIdx.x;
    if (i >= 16u * 256u * 1156u) return;
    unsigned int px = i % 34u;
    unsigned int rest = i / 34u;
    unsigned int py = rest % 34u;
    unsigned int bc = rest / 34u;
    int ch = bc & 255;
    unsigned short o = 0;
    if (py >= 1 && py <= 32 && px >= 1 && px <= 32) {
        float v = y1[(size_t)bc * 1024 + (py - 1) * 32 + (px - 1)];
        float yv = gamma[ch] * (v - mean[ch]) * rstd[ch] + beta[ch];
        yv = yv / (1.f + expf(-yv));
        o = f2bf(yv);
    }
    y1pb[i] = o;
}

// ---------------- final BN+SiLU on out, float4 vectorized ----------------
__global__ __launch_bounds__(256) void k_bnsilu4(float* __restrict__ data,
                                                 const float* __restrict__ mean,
                                                 const float* __restrict__ rstd,
                                                 const float* __restrict__ gamma,
                                                 const float* __restrict__ beta) {
    unsigned int i = blockIdx.x * 256 + threadIdx.x;  // float4 index, 4194304 total
    int ch = (int)((i >> 10) & 255u);
    float m = mean[ch], rs = rstd[ch], g = gamma[ch], bt = beta[ch];
    float4 v = ((float4*)data)[i];
    float y0 = g * (v.x - m) * rs + bt;
    float y1 = g * (v.y - m) * rs + bt;
    float y2 = g * (v.z - m) * rs + bt;
    float y3 = g * (v.w - m) * rs + bt;
    v.x = y0 / (1.f + expf(-y0));
    v.y = y1 / (1.f + expf(-y1));
    v.z = y2 / (1.f + expf(-y2));
    v.w = y3 / (1.f + expf(-y3));
    ((float4*)data)[i] = v;
}

extern "C" void kernel_launch(void* const* d_in, const int* in_sizes, int n_in,
                              void* d_out, int out_size, void* d_ws, size_t ws_size,
                              hipStream_t stream) {
    const float* x      = (const float*)d_in[0];
    const float* w_off  = (const float*)d_in[1];
    const float* b_off  = (const float*)d_in[2];
    const float* w_def  = (const float*)d_in[3];
    const float* b_def  = (const float*)d_in[4];
    const float* gamma1 = (const float*)d_in[5];
    const float* beta1  = (const float*)d_in[6];
    const float* w_dc   = (const float*)d_in[7];
    const float* gamma2 = (const float*)d_in[8];
    const float* beta2  = (const float*)d_in[9];
    float* out = (float*)d_out;

    char* base = (char*)d_ws;
    unsigned short* S    = (unsigned short*)base;                 // 75,497,472 B
    float*          y1   = (float*)(base + 75497472);             // 16,777,216 B
    unsigned short* y1pb = (unsigned short*)(base + 92274688);    //  9,469,952 B
    unsigned short* A1   = (unsigned short*)(base + 101744640);   //  1,179,648 B
    unsigned short* A2   = (unsigned short*)(base + 102924288);   //  2,097,152 B
    float*          off  = (float*)(base + 105021440);            //  1,179,648 B
    float*          stats = (float*)(base + 106201088);           //  1,024 B
    float* mean1 = stats, *rstd1 = stats + 256, *mean2 = stats + 512, *rstd2 = stats + 768;
    float* pstats = off;  // off is dead after k_sample; reuse for BN partials (32 KB)

    k_prep_a1<<<2304, 256, 0, stream>>>(w_def, A1);
    k_prep_a2<<<4096, 256, 0, stream>>>(w_dc, A2);
    k_offset_conv<<<dim3(16, 16), 576, 0, stream>>>(x, w_off, b_off, off);
    k_sample<<<dim3(16, 16, 2), 576, 0, stream>>>(x, off, S);
    k_gemm1<<<dim3(256, 2), 256, 0, stream>>>(A1, S, b_def, y1);
    k_bnstats_part<<<dim3(256, 16), 256, 0, stream>>>(y1, 1024, pstats);
    k_bnfin<<<1, 256, 0, stream>>>(pstats, 16384.f, mean1, rstd1);
    k_bnsilu_pad<<<18497, 256, 0, stream>>>(y1, mean1, rstd1, gamma1, beta1, y1pb);
    k_gemm2<<<dim3(128, 2, 4), 256, 0, stream>>>(A2, y1pb, out);
    k_bnstats_part<<<dim3(256, 16), 256, 0, stream>>>(out, 4096, pstats);
    k_bnfin<<<1, 256, 0, stream>>>(pstats, 65536.f, mean2, rstd2);
    k_bnsilu4<<<16384, 256, 0, stream>>>(out, mean2, rstd2, gamma2, beta2);
}

// Round 5
// 252.686 us; speedup vs baseline: 5.7510x; 1.3965x over previous
//
#include <hip/hip_runtime.h>
#include <math.h>

#ifdef __has_builtin
#if __has_builtin(__builtin_amdgcn_global_load_lds)
#define HAS_GLL 1
#endif
#endif
#ifndef HAS_GLL
#define HAS_GLL 0
#endif

typedef __attribute__((ext_vector_type(8))) short short8v;
typedef __attribute__((ext_vector_type(4))) float float4v;

__device__ __forceinline__ unsigned short f2bf(float f) {
    unsigned int u = __float_as_uint(f);
    u += 0x7fffu + ((u >> 16) & 1u);
    return (unsigned short)(u >> 16);
}

// wave stages 1KB into LDS: lane i -> ldsbase + 16*i, from per-lane gsrc (16B each)
__device__ __forceinline__ void stage1k(const void* gsrc, void* ldsbase) {
#if HAS_GLL
    __builtin_amdgcn_global_load_lds((const __attribute__((address_space(1))) unsigned int*)gsrc,
                                     (__attribute__((address_space(3))) unsigned int*)ldsbase,
                                     16, 0, 0);
#else
    int lane = threadIdx.x & 63;
    *(float4*)((char*)ldsbase + lane * 16) = *(const float4*)gsrc;
#endif
}

// ---------------- prep: xT[b][hw][c] = bf16(x[b][c][hw]) ----------------
__global__ __launch_bounds__(256) void k_prep_xt(const float* __restrict__ x,
                                                 unsigned short* __restrict__ xT) {
    int hw0 = blockIdx.x * 32, c0 = blockIdx.y * 32, b = blockIdx.z;
    int t = threadIdx.x;
    __shared__ unsigned short tl[32][36];
    {
        int c_l = t >> 3, w4 = (t & 7) * 4;
        float4 v = *(const float4*)&x[(size_t)((b * 256 + c0 + c_l) * 1024) + hw0 + w4];
        tl[c_l][w4 + 0] = f2bf(v.x);
        tl[c_l][w4 + 1] = f2bf(v.y);
        tl[c_l][w4 + 2] = f2bf(v.z);
        tl[c_l][w4 + 3] = f2bf(v.w);
    }
    __syncthreads();
    {
        int hw_l = t >> 3, c4 = (t & 7) * 4;
        unsigned int s0 = tl[c4 + 0][hw_l];
        unsigned int s1 = tl[c4 + 1][hw_l];
        unsigned int s2 = tl[c4 + 2][hw_l];
        unsigned int s3 = tl[c4 + 3][hw_l];
        uint2 pk;
        pk.x = s0 | (s1 << 16);
        pk.y = s2 | (s3 << 16);
        *(uint2*)&xT[(size_t)((b * 1024 + hw0 + hw_l) * 256) + c0 + c4] = pk;
    }
}

// ---------------- prep: A2off[cc8][tap][oc 32pad][c-slot 32] bf16, swizzle baked ----------------
__global__ void k_prep_aoff(const float* __restrict__ w_off, unsigned short* __restrict__ A2off) {
    int i = blockIdx.x * 256 + threadIdx.x;  // 73728 total
    int slot = i & 31;
    int oc = (i >> 5) & 31;
    int rest = i >> 10;
    int tap = rest % 9;
    int cc8 = rest / 9;
    int cgrp = (slot >> 3) ^ ((oc >> 1) & 3);
    int c = cc8 * 32 + (cgrp << 3) + (slot & 7);
    unsigned short v = 0;
    if (oc < 18) v = f2bf(w_off[(size_t)oc * 2304 + c * 9 + tap]);
    A2off[i] = v;
}

// ---------------- weight preps (fp32 -> bf16) ----------------
__global__ void k_prep_a1(const float* __restrict__ w_def, unsigned short* __restrict__ A1) {
    int i = blockIdx.x * 256 + threadIdx.x;  // 589824
    A1[i] = f2bf(w_def[i]);
}

__global__ void k_prep_a2(const float* __restrict__ w_dc, unsigned short* __restrict__ A2) {
    int i = blockIdx.x * 256 + threadIdx.x;  // 1048576
    int ci = i & 255;
    int tq = (i >> 8) & 3;
    int co = (i >> 10) & 255;
    int p  = i >> 18;
    int ph = p >> 1, pw = p & 1;
    int ty = tq >> 1, tx = tq & 1;
    int kh = 2 * ty + 1 - ph;
    int kw = 2 * tx + 1 - pw;
    A2[i] = f2bf(w_dc[((ci * 256 + co) * 4 + kh) * 4 + kw]);
}

// ---------------- offset conv as MFMA GEMM: M=32(pad of 18), N=64/block, K=2304 ----------------
// grid (16 hpair, 16 b), 256 threads = 4 waves; wave wid owns positions wid*16..+15
__global__ __launch_bounds__(256) void k_off_gemm(const unsigned short* __restrict__ A2off,
                                                  const unsigned short* __restrict__ xT,
                                                  const float* __restrict__ b_off,
                                                  float* __restrict__ off) {
    int hp = blockIdx.x, b = blockIdx.y;
    int h0 = hp * 2;
    int t = threadIdx.x;
    int lane = t & 63, wid = t >> 6;
    int l15 = lane & 15, g = lane >> 4;
    int swg = (l15 >> 1) & 3;
    __shared__ __align__(16) unsigned short As[9 * 32 * 32];   // [tap][oc][c-slot]
    __shared__ __align__(16) unsigned short Bsx[4 * 34 * 32];  // [row][col][c-slot swizzled]
    float4v acc[2];
    float4v z = {0.f, 0.f, 0.f, 0.f};
    acc[0] = z; acc[1] = z;

    int pos = wid * 16 + l15;
    int py = pos >> 5, px = pos & 31;

    for (int cc8 = 0; cc8 < 8; ++cc8) {
        __syncthreads();
        // stage A (linear, swizzle pre-baked in A2off)
        for (int idx = t; idx < 1152; idx += 256)
            stage1k(A2off + (size_t)cc8 * 9216 + idx * 8, (char*)As + idx * 16);
        // stage B: [4 rows][34 cols][4 groups], swizzled, zero halo
        for (int idx = t; idx < 544; idx += 256) {
            int r = idx / 136;
            int rem = idx - r * 136;
            int col = rem >> 2;
            int sgrp = rem & 3;
            int grp = sgrp ^ ((col >> 1) & 3);
            int h = h0 - 1 + r;
            int w = col - 1;
            uint4 v = {0u, 0u, 0u, 0u};
            if (h >= 0 && h < 32 && w >= 0 && w < 32)
                v = *(const uint4*)&xT[(size_t)((b * 1024 + h * 32 + w) * 256) + cc8 * 32 + grp * 8];
            *(uint4*)((char*)Bsx + ((r * 34 + col) << 6) + (sgrp << 4)) = v;
        }
        __syncthreads();
#pragma unroll
        for (int tap = 0; tap < 9; ++tap) {
            int ky = tap / 3, kx = tap - ky * 3;
            int col = px + kx;
            int rowr = py + ky;
            short8v bbf = *(const short8v*)((const char*)Bsx + ((rowr * 34 + col) << 6) +
                                            ((g ^ ((col >> 1) & 3)) << 4));
            short8v a0 = *(const short8v*)((const char*)As + tap * 2048 + l15 * 64 + ((g ^ swg) << 4));
            short8v a1 = *(const short8v*)((const char*)As + tap * 2048 + (16 + l15) * 64 + ((g ^ swg) << 4));
            acc[0] = __builtin_amdgcn_mfma_f32_16x16x32_bf16(a0, bbf, acc[0], 0, 0, 0);
            acc[1] = __builtin_amdgcn_mfma_f32_16x16x32_bf16(a1, bbf, acc[1], 0, 0, 0);
        }
    }
    int h = h0 + py;
#pragma unroll
    for (int r = 0; r < 4; ++r) {
        int oc = g * 4 + r;  // mi = 0: oc 0..15
        off[((size_t)(b * 18 + oc) << 10) + (h << 5) + px] = acc[0][r] + b_off[oc];
    }
    if (g == 0) {
#pragma unroll
        for (int r = 0; r < 2; ++r) {
            int oc = 16 + r;
            off[((size_t)(b * 18 + oc) << 10) + (h << 5) + px] = acc[1][r] + b_off[oc];
        }
    }
}

// ---------------- bilinear sampler: S[n][c*9+k] bf16 ----------------
__global__ __launch_bounds__(576) void k_sample(const float* __restrict__ x,
                                                const float* __restrict__ off,
                                                unsigned short* __restrict__ S) {
    int tile = blockIdx.x, b = blockIdx.y, cg = blockIdx.z;
    int t = threadIdx.x;
    int h0 = tile * 2;
    int n0 = b * 1024 + tile * 64;
    int cbase = cg * 128;
    int k = t >> 6;
    int pos = t & 63;
    int h = h0 + (pos >> 5), w = pos & 31;
    __shared__ __align__(16) float xpl[8 * 1156];
    __shared__ __align__(16) unsigned short sS[72 * 66];

    float dy = off[(b * 18 + 2 * k) * 1024 + h * 32 + w];
    float dx = off[(b * 18 + 2 * k + 1) * 1024 + h * 32 + w];
    float py = (float)(h + (k / 3) - 1) + dy;
    float px = (float)(w + (k % 3) - 1) + dx;
    float fy = floorf(py), fx = floorf(px);
    int y0i = (int)fy, x0i = (int)fx;
    float wy = py - fy, wx = px - fx;
    float vy0 = (y0i >= 0 && y0i < 32) ? 1.f : 0.f;
    float vy1 = (y0i >= -1 && y0i < 31) ? 1.f : 0.f;
    float vx0 = (x0i >= 0 && x0i < 32) ? 1.f : 0.f;
    float vx1 = (x0i >= -1 && x0i < 31) ? 1.f : 0.f;
    int y0c = min(max(y0i, 0), 31), y1c = min(max(y0i + 1, 0), 31);
    int x0c = min(max(x0i, 0), 31), x1c = min(max(x0i + 1, 0), 31);
    float w00 = (1.f - wy) * (1.f - wx) * vy0 * vx0;
    float w01 = (1.f - wy) * wx * vy0 * vx1;
    float w10 = wy * (1.f - wx) * vy1 * vx0;
    float w11 = wy * wx * vy1 * vx1;
    int a00 = y0c * 36 + x0c, a01 = y0c * 36 + x1c;
    int a10 = y1c * 36 + x0c, a11 = y1c * 36 + x1c;

    int wr_row = t / 9;
    int wr_ch  = t - wr_row * 9;

    for (int cc = cbase; cc < cbase + 128; cc += 8) {
        __syncthreads();
        for (int idx = t; idx < 2048; idx += 576) {
            int c_l = idx >> 8, r = (idx >> 3) & 31, x4 = (idx & 7) << 2;
            *(float4*)&xpl[c_l * 1156 + r * 36 + x4] =
                *(const float4*)&x[(size_t)((b * 256 + cc + c_l) * 32 + r) * 32 + x4];
        }
        __syncthreads();
#pragma unroll
        for (int c_l = 0; c_l < 8; ++c_l) {
            const float* pl = xpl + c_l * 1156;
            float v = w00 * pl[a00] + w01 * pl[a01] + w10 * pl[a10] + w11 * pl[a11];
            sS[(c_l * 9 + k) * 66 + pos] = f2bf(v);
        }
        __syncthreads();
        uint4 qv;
        {
            int base = wr_ch * 8;
            unsigned int s0 = sS[(base + 0) * 66 + wr_row];
            unsigned int s1 = sS[(base + 1) * 66 + wr_row];
            unsigned int s2 = sS[(base + 2) * 66 + wr_row];
            unsigned int s3 = sS[(base + 3) * 66 + wr_row];
            unsigned int s4 = sS[(base + 4) * 66 + wr_row];
            unsigned int s5 = sS[(base + 5) * 66 + wr_row];
            unsigned int s6 = sS[(base + 6) * 66 + wr_row];
            unsigned int s7 = sS[(base + 7) * 66 + wr_row];
            qv.x = s0 | (s1 << 16);
            qv.y = s2 | (s3 << 16);
            qv.z = s4 | (s5 << 16);
            qv.w = s6 | (s7 << 16);
        }
        *(uint4*)(S + (size_t)(n0 + wr_row) * 2304 + cc * 9 + wr_ch * 8) = qv;
    }
}

// ---------------- GEMM1: y1[co][n] = sum_K A1[co][K] * S[n][K], K=2304 ----------------
__global__ __launch_bounds__(256) void k_gemm1(const unsigned short* __restrict__ A1,
                                               const unsigned short* __restrict__ S,
                                               const float* __restrict__ b_def,
                                               float* __restrict__ y1) {
    int nb = blockIdx.x, mb = blockIdx.y;
    int t = threadIdx.x;
    int lane = t & 63, wid = t >> 6;
    int wm = wid >> 1, wn = wid & 1;
    __shared__ __align__(16) unsigned short As[128 * 32];
    __shared__ __align__(16) unsigned short Bs[64 * 32];
    int m0 = mb * 128, n0 = nb * 64;
    float4v acc[4][2];
    float4v z = {0.f, 0.f, 0.f, 0.f};
#pragma unroll
    for (int i = 0; i < 4; ++i) { acc[i][0] = z; acc[i][1] = z; }
    int rQ = lane >> 2;
    int qA = (lane & 3) ^ ((lane >> 3) & 3);  // pre-swizzled source group (m173 pattern)
    const unsigned short* gA0 = A1 + (size_t)(m0 + wid * 32 + rQ) * 2304 + qA * 8;
    const unsigned short* gA1 = gA0 + (size_t)16 * 2304;
    const unsigned short* gB0 = S + (size_t)(n0 + wid * 16 + rQ) * 2304 + qA * 8;
    unsigned short* lA0 = As + wid * 32 * 32;
    unsigned short* lA1 = As + (wid * 32 + 16) * 32;
    unsigned short* lB0 = Bs + wid * 16 * 32;
    int g = lane >> 4, l15 = lane & 15;
    int gs = (g ^ ((l15 >> 1) & 3)) << 4;
    for (int s = 0; s < 72; ++s) {
        __syncthreads();
        stage1k(gA0 + s * 32, lA0);
        stage1k(gA1 + s * 32, lA1);
        stage1k(gB0 + s * 32, lB0);
        __syncthreads();
        short8v a[4], bb[2];
#pragma unroll
        for (int mi = 0; mi < 4; ++mi)
            a[mi] = *(const short8v*)((const char*)As + ((wm * 64 + mi * 16 + l15) * 64 + gs));
#pragma unroll
        for (int ni = 0; ni < 2; ++ni)
            bb[ni] = *(const short8v*)((const char*)Bs + ((wn * 32 + ni * 16 + l15) * 64 + gs));
#pragma unroll
        for (int mi = 0; mi < 4; ++mi)
#pragma unroll
            for (int ni = 0; ni < 2; ++ni)
                acc[mi][ni] = __builtin_amdgcn_mfma_f32_16x16x32_bf16(a[mi], bb[ni], acc[mi][ni], 0, 0, 0);
    }
    int b = n0 >> 10;
    int posb = n0 & 1023;
#pragma unroll
    for (int mi = 0; mi < 4; ++mi) {
#pragma unroll
        for (int r = 0; r < 4; ++r) {
            int co = m0 + wm * 64 + mi * 16 + g * 4 + r;
            float bv = b_def[co];
            float* dst = y1 + ((size_t)(b * 256 + co) << 10) + posb;
#pragma unroll
            for (int ni = 0; ni < 2; ++ni)
                dst[wn * 32 + ni * 16 + l15] = acc[mi][ni][r] + bv;
        }
    }
}

// ---------------- GEMM2: convT by parity ----------------
__global__ __launch_bounds__(256) void k_gemm2(const unsigned short* __restrict__ A2,
                                               const unsigned short* __restrict__ y1pb,
                                               float* __restrict__ out) {
    int nb = blockIdx.x, mb = blockIdx.y, p = blockIdx.z;
    int ph = p >> 1, pw = p & 1;
    int t = threadIdx.x;
    int lane = t & 63, wid = t >> 6;
    int wm = wid >> 1, wn = wid & 1;
    __shared__ __align__(16) unsigned short As[128 * 32];
    __shared__ __align__(16) unsigned short Bs[128 * 32];
    int m0 = mb * 128, n0 = nb * 128;
    int b = n0 >> 10, pos0 = n0 & 1023, oh0 = pos0 >> 5;
    float4v acc[4][4];
    float4v z = {0.f, 0.f, 0.f, 0.f};
#pragma unroll
    for (int i = 0; i < 4; ++i)
#pragma unroll
        for (int j = 0; j < 4; ++j) acc[i][j] = z;
    int rQ = lane >> 2;
    int qA = (lane & 3) ^ ((lane >> 3) & 3);
    const unsigned short* gA0 = A2 + (size_t)(p * 256 + m0 + wid * 32 + rQ) * 1024 + qA * 8;
    const unsigned short* gA1 = gA0 + (size_t)16 * 1024;
    unsigned short* lA0 = As + wid * 32 * 32;
    unsigned short* lA1 = As + (wid * 32 + 16) * 32;
    int n_s = t & 31, cq = t >> 5;
    int g = lane >> 4, l15 = lane & 15;
    int gs = (g ^ ((l15 >> 1) & 3)) << 4;
    int wsw = ((cq >> 1) ^ ((n_s >> 1) & 3)) << 4;  // write-side swizzled group
    const int plane = 34 * 34;
    for (int s = 0; s < 32; ++s) {
        int tap = s >> 3, ci0 = (s & 7) * 32;
        int ty = tap >> 1, tx = tap & 1;
        int dy = ph ? (1 - ty) : (-ty);
        int dx = pw ? (1 - tx) : (-tx);
        __syncthreads();
        stage1k(gA0 + s * 32, lA0);
        stage1k(gA1 + s * 32, lA1);
        const unsigned short* srcbase = y1pb + (size_t)(b * 256 + ci0 + cq * 4) * plane;
        int iw1 = n_s + dx + 1;
#pragma unroll
        for (int pass = 0; pass < 4; ++pass) {
            int n_l = n_s + pass * 32;
            int ih1 = oh0 + pass + dy + 1;
            const unsigned short* sp = srcbase + ih1 * 34 + iw1;
            unsigned int v0 = sp[0];
            unsigned int v1 = sp[plane];
            unsigned int v2 = sp[2 * plane];
            unsigned int v3 = sp[3 * plane];
            uint2 pk;
            pk.x = v0 | (v1 << 16);
            pk.y = v2 | (v3 << 16);
            int boff = (n_l << 6) + wsw + ((cq & 1) << 3);
            *(uint2*)((char*)Bs + boff) = pk;
        }
        __syncthreads();
        short8v a[4], bb[4];
#pragma unroll
        for (int mi = 0; mi < 4; ++mi)
            a[mi] = *(const short8v*)((const char*)As + ((wm * 64 + mi * 16 + l15) * 64 + gs));
#pragma unroll
        for (int ni = 0; ni < 4; ++ni) {
            int nr = wn * 64 + ni * 16 + l15;
            bb[ni] = *(const short8v*)((const char*)Bs + (nr * 64 + gs));
        }
#pragma unroll
        for (int mi = 0; mi < 4; ++mi)
#pragma unroll
            for (int ni = 0; ni < 4; ++ni)
                acc[mi][ni] = __builtin_amdgcn_mfma_f32_16x16x32_bf16(a[mi], bb[ni], acc[mi][ni], 0, 0, 0);
    }
#pragma unroll
    for (int mi = 0; mi < 4; ++mi) {
#pragma unroll
        for (int r = 0; r < 4; ++r) {
            int co = m0 + wm * 64 + mi * 16 + g * 4 + r;
            float* dst = out + (size_t)(b * 256 + co) * 4096;
#pragma unroll
            for (int ni = 0; ni < 4; ++ni) {
                int nn = wn * 64 + ni * 16 + l15;
                int pos = pos0 + nn;
                int ohp = pos >> 5, owp = pos & 31;
                dst[(2 * ohp + ph) * 64 + 2 * owp + pw] = acc[mi][ni][r];
            }
        }
    }
}

// ---------------- BN stats: per-(ch,b) partials, then finisher ----------------
__global__ __launch_bounds__(256) void k_bnstats_part(const float* __restrict__ src, int hw,
                                                      float* __restrict__ pstats) {
    int ch = blockIdx.x, b = blockIdx.y;
    int t = threadIdx.x;
    const float* p = src + ((size_t)(b * 256 + ch)) * hw;
    float s = 0.f, s2 = 0.f;
    for (int i = t * 4; i < hw; i += 1024) {
        float4 v = *(const float4*)&p[i];
        s  += v.x + v.y + v.z + v.w;
        s2 += v.x * v.x + v.y * v.y + v.z * v.z + v.w * v.w;
    }
    __shared__ float rs[256], rs2[256];
    rs[t] = s; rs2[t] = s2;
    __syncthreads();
    for (int d = 128; d > 0; d >>= 1) {
        if (t < d) { rs[t] += rs[t + d]; rs2[t] += rs2[t + d]; }
        __syncthreads();
    }
    if (t == 0) {
        pstats[ch * 16 + b] = rs[0];
        pstats[4096 + ch * 16 + b] = rs2[0];
    }
}

__global__ __launch_bounds__(256) void k_bnfin(const float* __restrict__ pstats, float n,
                                               float* __restrict__ mean, float* __restrict__ rstd) {
    int ch = threadIdx.x;
    float s = 0.f, s2 = 0.f;
    for (int b = 0; b < 16; ++b) {
        s += pstats[ch * 16 + b];
        s2 += pstats[4096 + ch * 16 + b];
    }
    float m = s / n;
    float var = s2 / n - m * m;
    mean[ch] = m;
    rstd[ch] = rsqrtf(var + 1e-5f);
}

// ---------------- BN+SiLU on y1 -> padded bf16 (zero halo) ----------------
__global__ __launch_bounds__(256) void k_bnsilu_pad(const float* __restrict__ y1,
                                                    const float* __restrict__ mean,
                                                    const float* __restrict__ rstd,
                                                    const float* __restrict__ gamma,
                                                    const float* __restrict__ beta,
                                                    unsigned short* __restrict__ y1pb) {
    unsigned int i = blockIdx.x * 256 + threadIdx.x;
    if (i >= 16u * 256u * 1156u) return;
    unsigned int px = i % 34u;
    unsigned int rest = i / 34u;
    unsigned int py = rest % 34u;
    unsigned int bc = rest / 34u;
    int ch = bc & 255;
    unsigned short o = 0;
    if (py >= 1 && py <= 32 && px >= 1 && px <= 32) {
        float v = y1[(size_t)bc * 1024 + (py - 1) * 32 + (px - 1)];
        float yv = gamma[ch] * (v - mean[ch]) * rstd[ch] + beta[ch];
        yv = yv / (1.f + expf(-yv));
        o = f2bf(yv);
    }
    y1pb[i] = o;
}

// ---------------- final BN+SiLU on out, float4 vectorized ----------------
__global__ __launch_bounds__(256) void k_bnsilu4(float* __restrict__ data,
                                                 const float* __restrict__ mean,
                                                 const float* __restrict__ rstd,
                                                 const float* __restrict__ gamma,
                                                 const float* __restrict__ beta) {
    unsigned int i = blockIdx.x * 256 + threadIdx.x;  // float4 index, 4194304 total
    int ch = (int)((i >> 10) & 255u);
    float m = mean[ch], rs = rstd[ch], g = gamma[ch], bt = beta[ch];
    float4 v = ((float4*)data)[i];
    float y0 = g * (v.x - m) * rs + bt;
    float y1 = g * (v.y - m) * rs + bt;
    float y2 = g * (v.z - m) * rs + bt;
    float y3 = g * (v.w - m) * rs + bt;
    v.x = y0 / (1.f + expf(-y0));
    v.y = y1 / (1.f + expf(-y1));
    v.z = y2 / (1.f + expf(-y2));
    v.w = y3 / (1.f + expf(-y3));
    ((float4*)data)[i] = v;
}

extern "C" void kernel_launch(void* const* d_in, const int* in_sizes, int n_in,
                              void* d_out, int out_size, void* d_ws, size_t ws_size,
                              hipStream_t stream) {
    const float* x      = (const float*)d_in[0];
    const float* w_off  = (const float*)d_in[1];
    const float* b_off  = (const float*)d_in[2];
    const float* w_def  = (const float*)d_in[3];
    const float* b_def  = (const float*)d_in[4];
    const float* gamma1 = (const float*)d_in[5];
    const float* beta1  = (const float*)d_in[6];
    const float* w_dc   = (const float*)d_in[7];
    const float* gamma2 = (const float*)d_in[8];
    const float* beta2  = (const float*)d_in[9];
    float* out = (float*)d_out;

    char* base = (char*)d_ws;
    unsigned short* S    = (unsigned short*)base;                 // 75,497,472 B
    float*          y1   = (float*)(base + 75497472);             // 16,777,216 B
    unsigned short* y1pb = (unsigned short*)(base + 92274688);    //  9,469,952 B
    unsigned short* A1   = (unsigned short*)(base + 101744640);   //  1,179,648 B
    unsigned short* A2   = (unsigned short*)(base + 102924288);   //  2,097,152 B
    float*          off  = (float*)(base + 105021440);            //  1,179,648 B
    float*          stats = (float*)(base + 106201088);           //  1,024 B
    float* mean1 = stats, *rstd1 = stats + 256, *mean2 = stats + 512, *rstd2 = stats + 768;
    float* pstats = off;  // off region reused for BN partials after sampling
    // xT + A2off live inside the S region (S is written only later, by k_sample)
    unsigned short* xT    = (unsigned short*)base;                //  8,388,608 B
    unsigned short* A2off = (unsigned short*)(base + 8388608);    //    147,456 B

    k_prep_a1<<<2304, 256, 0, stream>>>(w_def, A1);
    k_prep_a2<<<4096, 256, 0, stream>>>(w_dc, A2);
    k_prep_aoff<<<288, 256, 0, stream>>>(w_off, A2off);
    k_prep_xt<<<dim3(32, 8, 16), 256, 0, stream>>>(x, xT);
    k_off_gemm<<<dim3(16, 16), 256, 0, stream>>>(A2off, xT, b_off, off);
    k_sample<<<dim3(16, 16, 2), 576, 0, stream>>>(x, off, S);
    k_gemm1<<<dim3(256, 2), 256, 0, stream>>>(A1, S, b_def, y1);
    k_bnstats_part<<<dim3(256, 16), 256, 0, stream>>>(y1, 1024, pstats);
    k_bnfin<<<1, 256, 0, stream>>>(pstats, 16384.f, mean1, rstd1);
    k_bnsilu_pad<<<18497, 256, 0, stream>>>(y1, mean1, rstd1, gamma1, beta1, y1pb);
    k_gemm2<<<dim3(128, 2, 4), 256, 0, stream>>>(A2, y1pb, out);
    k_bnstats_part<<<dim3(256, 16), 256, 0, stream>>>(out, 4096, pstats);
    k_bnfin<<<1, 256, 0, stream>>>(pstats, 65536.f, mean2, rstd2);
    k_bnsilu4<<<16384, 256, 0, stream>>>(out, mean2, rstd2, gamma2, beta2);
}

// Round 6
// 247.775 us; speedup vs baseline: 5.8650x; 1.0198x over previous
//
#include <hip/hip_runtime.h>
#include <math.h>

#ifdef __has_builtin
#if __has_builtin(__builtin_amdgcn_global_load_lds)
#define HAS_GLL 1
#endif
#endif
#ifndef HAS_GLL
#define HAS_GLL 0
#endif

typedef __attribute__((ext_vector_type(8))) short short8v;
typedef __attribute__((ext_vector_type(4))) float float4v;

__device__ __forceinline__ unsigned short f2bf(float f) {
    unsigned int u = __float_as_uint(f);
    u += 0x7fffu + ((u >> 16) & 1u);
    return (unsigned short)(u >> 16);
}

__device__ __forceinline__ float silu(float y) { return y / (1.f + expf(-y)); }

// wave stages 1KB into LDS: lane i -> ldsbase + 16*i, from per-lane gsrc (16B each)
__device__ __forceinline__ void stage1k(const void* gsrc, void* ldsbase) {
#if HAS_GLL
    __builtin_amdgcn_global_load_lds((const __attribute__((address_space(1))) unsigned int*)gsrc,
                                     (__attribute__((address_space(3))) unsigned int*)ldsbase,
                                     16, 0, 0);
#else
    int lane = threadIdx.x & 63;
    *(float4*)((char*)ldsbase + lane * 16) = *(const float4*)gsrc;
#endif
}

// ---------------- prep: xT[b][hw][c] = bf16(x[b][c][hw]) ----------------
__global__ __launch_bounds__(256) void k_prep_xt(const float* __restrict__ x,
                                                 unsigned short* __restrict__ xT) {
    int hw0 = blockIdx.x * 32, c0 = blockIdx.y * 32, b = blockIdx.z;
    int t = threadIdx.x;
    __shared__ unsigned short tl[32][36];
    {
        int c_l = t >> 3, w4 = (t & 7) * 4;
        float4 v = *(const float4*)&x[(size_t)((b * 256 + c0 + c_l) * 1024) + hw0 + w4];
        tl[c_l][w4 + 0] = f2bf(v.x);
        tl[c_l][w4 + 1] = f2bf(v.y);
        tl[c_l][w4 + 2] = f2bf(v.z);
        tl[c_l][w4 + 3] = f2bf(v.w);
    }
    __syncthreads();
    {
        int hw_l = t >> 3, c4 = (t & 7) * 4;
        unsigned int s0 = tl[c4 + 0][hw_l];
        unsigned int s1 = tl[c4 + 1][hw_l];
        unsigned int s2 = tl[c4 + 2][hw_l];
        unsigned int s3 = tl[c4 + 3][hw_l];
        uint2 pk;
        pk.x = s0 | (s1 << 16);
        pk.y = s2 | (s3 << 16);
        *(uint2*)&xT[(size_t)((b * 1024 + hw0 + hw_l) * 256) + c0 + c4] = pk;
    }
}

// ---------------- prep: A2off[cc8][tap][oc 32pad][c-slot 32] bf16, swizzle baked ----------------
__global__ void k_prep_aoff(const float* __restrict__ w_off, unsigned short* __restrict__ A2off) {
    int i = blockIdx.x * 256 + threadIdx.x;  // 73728 total
    int slot = i & 31;
    int oc = (i >> 5) & 31;
    int rest = i >> 10;
    int tap = rest % 9;
    int cc8 = rest / 9;
    int cgrp = (slot >> 3) ^ ((oc >> 1) & 3);
    int c = cc8 * 32 + (cgrp << 3) + (slot & 7);
    unsigned short v = 0;
    if (oc < 18) v = f2bf(w_off[(size_t)oc * 2304 + c * 9 + tap]);
    A2off[i] = v;
}

// ---------------- weight preps (fp32 -> bf16) ----------------
__global__ void k_prep_a1(const float* __restrict__ w_def, unsigned short* __restrict__ A1) {
    int i = blockIdx.x * 256 + threadIdx.x;  // 589824
    A1[i] = f2bf(w_def[i]);
}

__global__ void k_prep_a2(const float* __restrict__ w_dc, unsigned short* __restrict__ A2) {
    int i = blockIdx.x * 256 + threadIdx.x;  // 1048576
    int ci = i & 255;
    int tq = (i >> 8) & 3;
    int co = (i >> 10) & 255;
    int p  = i >> 18;
    int ph = p >> 1, pw = p & 1;
    int ty = tq >> 1, tx = tq & 1;
    int kh = 2 * ty + 1 - ph;
    int kw = 2 * tx + 1 - pw;
    A2[i] = f2bf(w_dc[((ci * 256 + co) * 4 + kh) * 4 + kw]);
}

// ---------------- offset conv as MFMA GEMM ----------------
__global__ __launch_bounds__(256) void k_off_gemm(const unsigned short* __restrict__ A2off,
                                                  const unsigned short* __restrict__ xT,
                                                  const float* __restrict__ b_off,
                                                  float* __restrict__ off) {
    int hp = blockIdx.x, b = blockIdx.y;
    int h0 = hp * 2;
    int t = threadIdx.x;
    int lane = t & 63, wid = t >> 6;
    int l15 = lane & 15, g = lane >> 4;
    int swg = (l15 >> 1) & 3;
    __shared__ __align__(16) unsigned short As[9 * 32 * 32];
    __shared__ __align__(16) unsigned short Bsx[4 * 34 * 32];
    float4v acc[2];
    float4v z = {0.f, 0.f, 0.f, 0.f};
    acc[0] = z; acc[1] = z;

    int pos = wid * 16 + l15;
    int py = pos >> 5, px = pos & 31;

    for (int cc8 = 0; cc8 < 8; ++cc8) {
        __syncthreads();
        for (int idx = t; idx < 1152; idx += 256)
            stage1k(A2off + (size_t)cc8 * 9216 + idx * 8, (char*)As + idx * 16);
        for (int idx = t; idx < 544; idx += 256) {
            int r = idx / 136;
            int rem = idx - r * 136;
            int col = rem >> 2;
            int sgrp = rem & 3;
            int grp = sgrp ^ ((col >> 1) & 3);
            int h = h0 - 1 + r;
            int w = col - 1;
            uint4 v = {0u, 0u, 0u, 0u};
            if (h >= 0 && h < 32 && w >= 0 && w < 32)
                v = *(const uint4*)&xT[(size_t)((b * 1024 + h * 32 + w) * 256) + cc8 * 32 + grp * 8];
            *(uint4*)((char*)Bsx + ((r * 34 + col) << 6) + (sgrp << 4)) = v;
        }
        __syncthreads();
#pragma unroll
        for (int tap = 0; tap < 9; ++tap) {
            int ky = tap / 3, kx = tap - ky * 3;
            int col = px + kx;
            int rowr = py + ky;
            short8v bbf = *(const short8v*)((const char*)Bsx + ((rowr * 34 + col) << 6) +
                                            ((g ^ ((col >> 1) & 3)) << 4));
            short8v a0 = *(const short8v*)((const char*)As + tap * 2048 + l15 * 64 + ((g ^ swg) << 4));
            short8v a1 = *(const short8v*)((const char*)As + tap * 2048 + (16 + l15) * 64 + ((g ^ swg) << 4));
            acc[0] = __builtin_amdgcn_mfma_f32_16x16x32_bf16(a0, bbf, acc[0], 0, 0, 0);
            acc[1] = __builtin_amdgcn_mfma_f32_16x16x32_bf16(a1, bbf, acc[1], 0, 0, 0);
        }
    }
    int h = h0 + py;
#pragma unroll
    for (int r = 0; r < 4; ++r) {
        int oc = g * 4 + r;
        off[((size_t)(b * 18 + oc) << 10) + (h << 5) + px] = acc[0][r] + b_off[oc];
    }
    if (g == 0) {
#pragma unroll
        for (int r = 0; r < 2; ++r) {
            int oc = 16 + r;
            off[((size_t)(b * 18 + oc) << 10) + (h << 5) + px] = acc[1][r] + b_off[oc];
        }
    }
}

// ---------------- bilinear sampler: S[n][c*9+k] bf16 ----------------
__global__ __launch_bounds__(576) void k_sample(const float* __restrict__ x,
                                                const float* __restrict__ off,
                                                unsigned short* __restrict__ S) {
    int tile = blockIdx.x, b = blockIdx.y, cg = blockIdx.z;
    int t = threadIdx.x;
    int h0 = tile * 2;
    int n0 = b * 1024 + tile * 64;
    int cbase = cg * 128;
    int k = t >> 6;
    int pos = t & 63;
    int h = h0 + (pos >> 5), w = pos & 31;
    __shared__ __align__(16) float xpl[8 * 1156];
    __shared__ __align__(16) unsigned short sS[72 * 66];

    float dy = off[(b * 18 + 2 * k) * 1024 + h * 32 + w];
    float dx = off[(b * 18 + 2 * k + 1) * 1024 + h * 32 + w];
    float py = (float)(h + (k / 3) - 1) + dy;
    float px = (float)(w + (k % 3) - 1) + dx;
    float fy = floorf(py), fx = floorf(px);
    int y0i = (int)fy, x0i = (int)fx;
    float wy = py - fy, wx = px - fx;
    float vy0 = (y0i >= 0 && y0i < 32) ? 1.f : 0.f;
    float vy1 = (y0i >= -1 && y0i < 31) ? 1.f : 0.f;
    float vx0 = (x0i >= 0 && x0i < 32) ? 1.f : 0.f;
    float vx1 = (x0i >= -1 && x0i < 31) ? 1.f : 0.f;
    int y0c = min(max(y0i, 0), 31), y1c = min(max(y0i + 1, 0), 31);
    int x0c = min(max(x0i, 0), 31), x1c = min(max(x0i + 1, 0), 31);
    float w00 = (1.f - wy) * (1.f - wx) * vy0 * vx0;
    float w01 = (1.f - wy) * wx * vy0 * vx1;
    float w10 = wy * (1.f - wx) * vy1 * vx0;
    float w11 = wy * wx * vy1 * vx1;
    int a00 = y0c * 36 + x0c, a01 = y0c * 36 + x1c;
    int a10 = y1c * 36 + x0c, a11 = y1c * 36 + x1c;

    int wr_row = t / 9;
    int wr_ch  = t - wr_row * 9;

    for (int cc = cbase; cc < cbase + 128; cc += 8) {
        __syncthreads();
        for (int idx = t; idx < 2048; idx += 576) {
            int c_l = idx >> 8, r = (idx >> 3) & 31, x4 = (idx & 7) << 2;
            *(float4*)&xpl[c_l * 1156 + r * 36 + x4] =
                *(const float4*)&x[(size_t)((b * 256 + cc + c_l) * 32 + r) * 32 + x4];
        }
        __syncthreads();
#pragma unroll
        for (int c_l = 0; c_l < 8; ++c_l) {
            const float* pl = xpl + c_l * 1156;
            float v = w00 * pl[a00] + w01 * pl[a01] + w10 * pl[a10] + w11 * pl[a11];
            sS[(c_l * 9 + k) * 66 + pos] = f2bf(v);
        }
        __syncthreads();
        uint4 qv;
        {
            int base = wr_ch * 8;
            unsigned int s0 = sS[(base + 0) * 66 + wr_row];
            unsigned int s1 = sS[(base + 1) * 66 + wr_row];
            unsigned int s2 = sS[(base + 2) * 66 + wr_row];
            unsigned int s3 = sS[(base + 3) * 66 + wr_row];
            unsigned int s4 = sS[(base + 4) * 66 + wr_row];
            unsigned int s5 = sS[(base + 5) * 66 + wr_row];
            unsigned int s6 = sS[(base + 6) * 66 + wr_row];
            unsigned int s7 = sS[(base + 7) * 66 + wr_row];
            qv.x = s0 | (s1 << 16);
            qv.y = s2 | (s3 << 16);
            qv.z = s4 | (s5 << 16);
            qv.w = s6 | (s7 << 16);
        }
        *(uint4*)(S + (size_t)(n0 + wr_row) * 2304 + cc * 9 + wr_ch * 8) = qv;
    }
}

// ---------------- GEMM1: y1[co][n] = sum_K A1[co][K] * S[n][K], K=2304 ----------------
__global__ __launch_bounds__(256) void k_gemm1(const unsigned short* __restrict__ A1,
                                               const unsigned short* __restrict__ S,
                                               const float* __restrict__ b_def,
                                               float* __restrict__ y1) {
    int nb = blockIdx.x, mb = blockIdx.y;
    int t = threadIdx.x;
    int lane = t & 63, wid = t >> 6;
    int wm = wid >> 1, wn = wid & 1;
    __shared__ __align__(16) unsigned short As[128 * 32];
    __shared__ __align__(16) unsigned short Bs[64 * 32];
    int m0 = mb * 128, n0 = nb * 64;
    float4v acc[4][2];
    float4v z = {0.f, 0.f, 0.f, 0.f};
#pragma unroll
    for (int i = 0; i < 4; ++i) { acc[i][0] = z; acc[i][1] = z; }
    int rQ = lane >> 2;
    int qA = (lane & 3) ^ ((lane >> 3) & 3);
    const unsigned short* gA0 = A1 + (size_t)(m0 + wid * 32 + rQ) * 2304 + qA * 8;
    const unsigned short* gA1 = gA0 + (size_t)16 * 2304;
    const unsigned short* gB0 = S + (size_t)(n0 + wid * 16 + rQ) * 2304 + qA * 8;
    unsigned short* lA0 = As + wid * 32 * 32;
    unsigned short* lA1 = As + (wid * 32 + 16) * 32;
    unsigned short* lB0 = Bs + wid * 16 * 32;
    int g = lane >> 4, l15 = lane & 15;
    int gs = (g ^ ((l15 >> 1) & 3)) << 4;
    for (int s = 0; s < 72; ++s) {
        __syncthreads();
        stage1k(gA0 + s * 32, lA0);
        stage1k(gA1 + s * 32, lA1);
        stage1k(gB0 + s * 32, lB0);
        __syncthreads();
        short8v a[4], bb[2];
#pragma unroll
        for (int mi = 0; mi < 4; ++mi)
            a[mi] = *(const short8v*)((const char*)As + ((wm * 64 + mi * 16 + l15) * 64 + gs));
#pragma unroll
        for (int ni = 0; ni < 2; ++ni)
            bb[ni] = *(const short8v*)((const char*)Bs + ((wn * 32 + ni * 16 + l15) * 64 + gs));
#pragma unroll
        for (int mi = 0; mi < 4; ++mi)
#pragma unroll
            for (int ni = 0; ni < 2; ++ni)
                acc[mi][ni] = __builtin_amdgcn_mfma_f32_16x16x32_bf16(a[mi], bb[ni], acc[mi][ni], 0, 0, 0);
    }
    int b = n0 >> 10;
    int posb = n0 & 1023;
#pragma unroll
    for (int mi = 0; mi < 4; ++mi) {
#pragma unroll
        for (int r = 0; r < 4; ++r) {
            int co = m0 + wm * 64 + mi * 16 + g * 4 + r;
            float bv = b_def[co];
            float* dst = y1 + ((size_t)(b * 256 + co) << 10) + posb;
#pragma unroll
            for (int ni = 0; ni < 2; ++ni)
                dst[wn * 32 + ni * 16 + l15] = acc[mi][ni][r] + bv;
        }
    }
}

// ---------------- GEMM2 v2: convT by parity, channel-last B, K_STEP=64 ----------------
// grid (128 nb, 2 mb, 4 p), 256 threads = 4 waves (2m x 2n)
__global__ __launch_bounds__(256) void k_gemm2(const unsigned short* __restrict__ A2,
                                               const unsigned short* __restrict__ y1T,
                                               float* __restrict__ outP) {
    int nb = blockIdx.x, mb = blockIdx.y, p = blockIdx.z;
    int ph = p >> 1, pw = p & 1;
    int t = threadIdx.x;
    int lane = t & 63, wid = t >> 6;
    int wm = wid >> 1, wn = wid & 1;
    int l15 = lane & 15, g = lane >> 4;
    __shared__ __align__(16) unsigned short As[128 * 64];
    __shared__ __align__(16) unsigned short Bs[128 * 64];
    int m0 = mb * 128, n0 = nb * 128;
    int b = n0 >> 10, pos0 = n0 & 1023, oh0 = pos0 >> 5;

    int dtab[4];
#pragma unroll
    for (int tap = 0; tap < 4; ++tap) {
        int ty = tap >> 1, tx = tap & 1;
        int dy = ph ? (1 - ty) : (-ty);
        int dx = pw ? (1 - tx) : (-tx);
        dtab[tap] = (dy * 34 + dx) * 256;
    }
    const unsigned short* srcA[4];
    const unsigned short* srcB[4];
    unsigned short* dstA[4];
    unsigned short* dstB[4];
#pragma unroll
    for (int it = 0; it < 4; ++it) {
        int idx = t + it * 256;
        int r = idx >> 3, s8 = idx & 7, c = s8 ^ (r & 7);
        srcA[it] = A2 + (size_t)(p * 256 + m0 + r) * 1024 + c * 8;
        dstA[it] = As + idx * 8;
        int ih = oh0 + (r >> 5) + 1;
        int iw = (r & 31) + 1;
        srcB[it] = y1T + ((size_t)(b * 34 + ih) * 34 + iw) * 256 + c * 8;
        dstB[it] = Bs + idx * 8;
    }

    float4v acc[4][4];
    float4v z = {0.f, 0.f, 0.f, 0.f};
#pragma unroll
    for (int i = 0; i < 4; ++i)
#pragma unroll
        for (int j = 0; j < 4; ++j) acc[i][j] = z;

    for (int step = 0; step < 16; ++step) {
        int tap = step >> 2;
        int koff = step * 64;
        int boff = dtab[tap] + (step & 3) * 64;
        __syncthreads();
#pragma unroll
        for (int it = 0; it < 4; ++it) {
            stage1k(srcA[it] + koff, dstA[it]);
            stage1k(srcB[it] + boff, dstB[it]);
        }
        __syncthreads();
#pragma unroll
        for (int kk = 0; kk < 2; ++kk) {
            short8v a[4], bb[4];
#pragma unroll
            for (int mi = 0; mi < 4; ++mi) {
                int row = wm * 64 + mi * 16 + l15;
                int slot = ((kk << 2) + g) ^ (row & 7);
                a[mi] = *(const short8v*)((const char*)As + row * 128 + slot * 16);
            }
#pragma unroll
            for (int ni = 0; ni < 4; ++ni) {
                int row = wn * 64 + ni * 16 + l15;
                int slot = ((kk << 2) + g) ^ (row & 7);
                bb[ni] = *(const short8v*)((const char*)Bs + row * 128 + slot * 16);
            }
#pragma unroll
            for (int mi = 0; mi < 4; ++mi)
#pragma unroll
                for (int ni = 0; ni < 4; ++ni)
                    acc[mi][ni] = __builtin_amdgcn_mfma_f32_16x16x32_bf16(a[mi], bb[ni], acc[mi][ni], 0, 0, 0);
        }
    }
    // coalesced unit-stride write to parity-planar outP
#pragma unroll
    for (int mi = 0; mi < 4; ++mi) {
#pragma unroll
        for (int r = 0; r < 4; ++r) {
            int co = m0 + wm * 64 + mi * 16 + g * 4 + r;
            float* dst = outP + ((size_t)((p * 16 + b) * 256 + co) << 10) + pos0;
#pragma unroll
            for (int ni = 0; ni < 4; ++ni)
                dst[wn * 64 + ni * 16 + l15] = acc[mi][ni][r];
        }
    }
}

// ---------------- BN stats: per-(ch,plane) partials, then finisher ----------------
__global__ __launch_bounds__(256) void k_bnstats_part(const float* __restrict__ src, int nparts,
                                                      float* __restrict__ pstats) {
    int ch = blockIdx.x, j = blockIdx.y;
    int t = threadIdx.x;
    const float* p = src + ((size_t)(j * 256 + ch) << 10);
    float4 v = *(const float4*)&p[t * 4];
    float s  = v.x + v.y + v.z + v.w;
    float s2 = v.x * v.x + v.y * v.y + v.z * v.z + v.w * v.w;
    __shared__ float rs[256], rs2[256];
    rs[t] = s; rs2[t] = s2;
    __syncthreads();
    for (int d = 128; d > 0; d >>= 1) {
        if (t < d) { rs[t] += rs[t + d]; rs2[t] += rs2[t + d]; }
        __syncthreads();
    }
    if (t == 0) {
        pstats[ch * nparts + j] = rs[0];
        pstats[256 * nparts + ch * nparts + j] = rs2[0];
    }
}

__global__ __launch_bounds__(256) void k_bnfin(const float* __restrict__ pstats, int nparts, float n,
                                               float* __restrict__ mean, float* __restrict__ rstd) {
    int ch = threadIdx.x;
    float s = 0.f, s2 = 0.f;
    for (int j = 0; j < nparts; ++j) {
        s += pstats[ch * nparts + j];
        s2 += pstats[256 * nparts + ch * nparts + j];
    }
    float m = s / n;
    float var = s2 / n - m * m;
    mean[ch] = m;
    rstd[ch] = rsqrtf(var + 1e-5f);
}

// ---------------- BN+SiLU on y1 -> channel-last padded bf16 y1T[b][34][34][256] ----------------
// grid (32 py, 8 cg, 16 b), 256 threads
__global__ __launch_bounds__(256) void k_bnsilu_padT(const float* __restrict__ y1,
                                                     const float* __restrict__ mean,
                                                     const float* __restrict__ rstd,
                                                     const float* __restrict__ gamma,
                                                     const float* __restrict__ beta,
                                                     unsigned short* __restrict__ y1T) {
    int py = blockIdx.x, cg = blockIdx.y, b = blockIdx.z;
    int c0 = cg * 32;
    int t = threadIdx.x;
    __shared__ unsigned short tl[32][36];
    {
        int c_l = t >> 3, px4 = (t & 7) * 4;
        int ch = c0 + c_l;
        float m = mean[ch], rs = rstd[ch], ga = gamma[ch], be = beta[ch];
        float4 v = *(const float4*)&y1[(size_t)((b * 256 + ch) << 10) + (py << 5) + px4];
        tl[c_l][px4 + 0] = f2bf(silu(ga * (v.x - m) * rs + be));
        tl[c_l][px4 + 1] = f2bf(silu(ga * (v.y - m) * rs + be));
        tl[c_l][px4 + 2] = f2bf(silu(ga * (v.z - m) * rs + be));
        tl[c_l][px4 + 3] = f2bf(silu(ga * (v.w - m) * rs + be));
    }
    __syncthreads();
    {
        int px = t >> 3, c4 = (t & 7) * 4;
        unsigned int s0 = tl[c4 + 0][px];
        unsigned int s1 = tl[c4 + 1][px];
        unsigned int s2 = tl[c4 + 2][px];
        unsigned int s3 = tl[c4 + 3][px];
        uint2 pk;
        pk.x = s0 | (s1 << 16);
        pk.y = s2 | (s3 << 16);
        *(uint2*)&y1T[((size_t)(b * 34 + py + 1) * 34 + (px + 1)) * 256 + c0 + c4] = pk;
    }
}

// ---------------- final: BN+SiLU + parity interleave -> out ----------------
__global__ __launch_bounds__(256) void k_bnsilu_out(const float* __restrict__ outP,
                                                    const float* __restrict__ mean,
                                                    const float* __restrict__ rstd,
                                                    const float* __restrict__ gamma,
                                                    const float* __restrict__ beta,
                                                    float* __restrict__ out) {
    unsigned int i = blockIdx.x * 256 + threadIdx.x;  // float4 index, 4194304 total
    int ow4 = i & 15;
    int oh = (i >> 4) & 63;
    int co = (i >> 10) & 255;
    int b  = i >> 18;
    int p0 = (oh & 1) * 2;
    int pos = ((oh >> 1) << 5) + ow4 * 2;
    const float* pl0 = outP + ((size_t)((p0 * 16 + b) * 256 + co) << 10) + pos;
    const float* pl1 = pl0 + ((size_t)16 * 256 << 10);
    float2 e = *(const float2*)pl0;
    float2 o = *(const float2*)pl1;
    float m = mean[co], rs = rstd[co], ga = gamma[co], be = beta[co];
    float4 v;
    v.x = silu(ga * (e.x - m) * rs + be);
    v.y = silu(ga * (o.x - m) * rs + be);
    v.z = silu(ga * (e.y - m) * rs + be);
    v.w = silu(ga * (o.y - m) * rs + be);
    *(float4*)&out[((size_t)(b * 256 + co) << 12) + (oh << 6) + ow4 * 4] = v;
}

extern "C" void kernel_launch(void* const* d_in, const int* in_sizes, int n_in,
                              void* d_out, int out_size, void* d_ws, size_t ws_size,
                              hipStream_t stream) {
    const float* x      = (const float*)d_in[0];
    const float* w_off  = (const float*)d_in[1];
    const float* b_off  = (const float*)d_in[2];
    const float* w_def  = (const float*)d_in[3];
    const float* b_def  = (const float*)d_in[4];
    const float* gamma1 = (const float*)d_in[5];
    const float* beta1  = (const float*)d_in[6];
    const float* w_dc   = (const float*)d_in[7];
    const float* gamma2 = (const float*)d_in[8];
    const float* beta2  = (const float*)d_in[9];
    float* out = (float*)d_out;

    char* base = (char*)d_ws;
    unsigned short* S    = (unsigned short*)base;                 // 75,497,472 B (dead after gemm1)
    float*          y1   = (float*)(base + 75497472);             // 16,777,216 B
    unsigned short* y1T  = (unsigned short*)(base + 92274688);    //  9,469,952 B (padded ch-last)
    unsigned short* A1   = (unsigned short*)(base + 101744640);   //  1,179,648 B
    unsigned short* A2   = (unsigned short*)(base + 102924288);   //  2,097,152 B
    float*          off  = (float*)(base + 105021440);            //  1,179,648 B
    float*          stats = (float*)(base + 106201088);           //  1,024 B
    float* mean1 = stats, *rstd1 = stats + 256, *mean2 = stats + 512, *rstd2 = stats + 768;
    float* pstats = off;                       // dead after k_sample; 128 KB needed
    unsigned short* xT    = (unsigned short*)base;                //  8,388,608 B (dead after off_gemm)
    unsigned short* A2off = (unsigned short*)(base + 8388608);    //    147,456 B
    float* outP = (float*)base;                // 67,108,864 B, aliases S after gemm1

    k_prep_a1<<<2304, 256, 0, stream>>>(w_def, A1);
    k_prep_a2<<<4096, 256, 0, stream>>>(w_dc, A2);
    k_prep_aoff<<<288, 256, 0, stream>>>(w_off, A2off);
    k_prep_xt<<<dim3(32, 8, 16), 256, 0, stream>>>(x, xT);
    k_off_gemm<<<dim3(16, 16), 256, 0, stream>>>(A2off, xT, b_off, off);
    k_sample<<<dim3(16, 16, 2), 576, 0, stream>>>(x, off, S);
    k_gemm1<<<dim3(256, 2), 256, 0, stream>>>(A1, S, b_def, y1);
    k_bnstats_part<<<dim3(256, 16), 256, 0, stream>>>(y1, 16, pstats);
    k_bnfin<<<1, 256, 0, stream>>>(pstats, 16, 16384.f, mean1, rstd1);
    hipMemsetAsync(y1T, 0, 9469952, stream);   // zero halo for y1T
    k_bnsilu_padT<<<dim3(32, 8, 16), 256, 0, stream>>>(y1, mean1, rstd1, gamma1, beta1, y1T);
    k_gemm2<<<dim3(128, 2, 4), 256, 0, stream>>>(A2, y1T, outP);
    k_bnstats_part<<<dim3(256, 64), 256, 0, stream>>>(outP, 64, pstats);
    k_bnfin<<<1, 256, 0, stream>>>(pstats, 64, 65536.f, mean2, rstd2);
    k_bnsilu_out<<<16384, 256, 0, stream>>>(outP, mean2, rstd2, gamma2, beta2, out);
}

// Round 7
// 212.407 us; speedup vs baseline: 6.8416x; 1.1665x over previous
//
#include <hip/hip_runtime.h>
#include <math.h>

#ifdef __has_builtin
#if __has_builtin(__builtin_amdgcn_global_load_lds)
#define HAS_GLL 1
#endif
#endif
#ifndef HAS_GLL
#define HAS_GLL 0
#endif

typedef __attribute__((ext_vector_type(8))) short short8v;
typedef __attribute__((ext_vector_type(4))) float float4v;

__device__ __forceinline__ unsigned short f2bf(float f) {
    unsigned int u = __float_as_uint(f);
    u += 0x7fffu + ((u >> 16) & 1u);
    return (unsigned short)(u >> 16);
}

__device__ __forceinline__ float silu(float y) { return y / (1.f + expf(-y)); }

// wave stages 1KB into LDS: lane i -> ldsbase + 16*i, from per-lane gsrc (16B each)
__device__ __forceinline__ void stage1k(const void* gsrc, void* ldsbase) {
#if HAS_GLL
    __builtin_amdgcn_global_load_lds((const __attribute__((address_space(1))) unsigned int*)gsrc,
                                     (__attribute__((address_space(3))) unsigned int*)ldsbase,
                                     16, 0, 0);
#else
    int lane = threadIdx.x & 63;
    *(float4*)((char*)ldsbase + lane * 16) = *(const float4*)gsrc;
#endif
}

// ---------------- prep: xT[b][hw][c] = bf16(x[b][c][hw]) ----------------
__global__ __launch_bounds__(256) void k_prep_xt(const float* __restrict__ x,
                                                 unsigned short* __restrict__ xT) {
    int hw0 = blockIdx.x * 32, c0 = blockIdx.y * 32, b = blockIdx.z;
    int t = threadIdx.x;
    __shared__ unsigned short tl[32][36];
    {
        int c_l = t >> 3, w4 = (t & 7) * 4;
        float4 v = *(const float4*)&x[(size_t)((b * 256 + c0 + c_l) * 1024) + hw0 + w4];
        tl[c_l][w4 + 0] = f2bf(v.x);
        tl[c_l][w4 + 1] = f2bf(v.y);
        tl[c_l][w4 + 2] = f2bf(v.z);
        tl[c_l][w4 + 3] = f2bf(v.w);
    }
    __syncthreads();
    {
        int hw_l = t >> 3, c4 = (t & 7) * 4;
        unsigned int s0 = tl[c4 + 0][hw_l];
        unsigned int s1 = tl[c4 + 1][hw_l];
        unsigned int s2 = tl[c4 + 2][hw_l];
        unsigned int s3 = tl[c4 + 3][hw_l];
        uint2 pk;
        pk.x = s0 | (s1 << 16);
        pk.y = s2 | (s3 << 16);
        *(uint2*)&xT[(size_t)((b * 1024 + hw0 + hw_l) * 256) + c0 + c4] = pk;
    }
}

// ---------------- prep: A2off[cc8][tap][oc 32pad][c-slot 32] bf16, swizzle baked ----------------
__global__ void k_prep_aoff(const float* __restrict__ w_off, unsigned short* __restrict__ A2off) {
    int i = blockIdx.x * 256 + threadIdx.x;  // 73728 total
    int slot = i & 31;
    int oc = (i >> 5) & 31;
    int rest = i >> 10;
    int tap = rest % 9;
    int cc8 = rest / 9;
    int cgrp = (slot >> 3) ^ ((oc >> 1) & 3);
    int c = cc8 * 32 + (cgrp << 3) + (slot & 7);
    unsigned short v = 0;
    if (oc < 18) v = f2bf(w_off[(size_t)oc * 2304 + c * 9 + tap]);
    A2off[i] = v;
}

// ---------------- weight preps (fp32 -> bf16) ----------------
__global__ void k_prep_a1(const float* __restrict__ w_def, unsigned short* __restrict__ A1) {
    int i = blockIdx.x * 256 + threadIdx.x;  // 589824
    A1[i] = f2bf(w_def[i]);
}

__global__ void k_prep_a2(const float* __restrict__ w_dc, unsigned short* __restrict__ A2) {
    int i = blockIdx.x * 256 + threadIdx.x;  // 1048576
    int ci = i & 255;
    int tq = (i >> 8) & 3;
    int co = (i >> 10) & 255;
    int p  = i >> 18;
    int ph = p >> 1, pw = p & 1;
    int ty = tq >> 1, tx = tq & 1;
    int kh = 2 * ty + 1 - ph;
    int kw = 2 * tx + 1 - pw;
    A2[i] = f2bf(w_dc[((ci * 256 + co) * 4 + kh) * 4 + kw]);
}

// ---------------- offset conv as MFMA GEMM ----------------
__global__ __launch_bounds__(256) void k_off_gemm(const unsigned short* __restrict__ A2off,
                                                  const unsigned short* __restrict__ xT,
                                                  const float* __restrict__ b_off,
                                                  float* __restrict__ off) {
    int hp = blockIdx.x, b = blockIdx.y;
    int h0 = hp * 2;
    int t = threadIdx.x;
    int lane = t & 63, wid = t >> 6;
    int l15 = lane & 15, g = lane >> 4;
    int swg = (l15 >> 1) & 3;
    __shared__ __align__(16) unsigned short As[9 * 32 * 32];
    __shared__ __align__(16) unsigned short Bsx[4 * 34 * 32];
    float4v acc[2];
    float4v z = {0.f, 0.f, 0.f, 0.f};
    acc[0] = z; acc[1] = z;

    int pos = wid * 16 + l15;
    int py = pos >> 5, px = pos & 31;

    for (int cc8 = 0; cc8 < 8; ++cc8) {
        __syncthreads();
        for (int idx = t; idx < 1152; idx += 256)
            stage1k(A2off + (size_t)cc8 * 9216 + idx * 8, (char*)As + idx * 16);
        for (int idx = t; idx < 544; idx += 256) {
            int r = idx / 136;
            int rem = idx - r * 136;
            int col = rem >> 2;
            int sgrp = rem & 3;
            int grp = sgrp ^ ((col >> 1) & 3);
            int h = h0 - 1 + r;
            int w = col - 1;
            uint4 v = {0u, 0u, 0u, 0u};
            if (h >= 0 && h < 32 && w >= 0 && w < 32)
                v = *(const uint4*)&xT[(size_t)((b * 1024 + h * 32 + w) * 256) + cc8 * 32 + grp * 8];
            *(uint4*)((char*)Bsx + ((r * 34 + col) << 6) + (sgrp << 4)) = v;
        }
        __syncthreads();
#pragma unroll
        for (int tap = 0; tap < 9; ++tap) {
            int ky = tap / 3, kx = tap - ky * 3;
            int col = px + kx;
            int rowr = py + ky;
            short8v bbf = *(const short8v*)((const char*)Bsx + ((rowr * 34 + col) << 6) +
                                            ((g ^ ((col >> 1) & 3)) << 4));
            short8v a0 = *(const short8v*)((const char*)As + tap * 2048 + l15 * 64 + ((g ^ swg) << 4));
            short8v a1 = *(const short8v*)((const char*)As + tap * 2048 + (16 + l15) * 64 + ((g ^ swg) << 4));
            acc[0] = __builtin_amdgcn_mfma_f32_16x16x32_bf16(a0, bbf, acc[0], 0, 0, 0);
            acc[1] = __builtin_amdgcn_mfma_f32_16x16x32_bf16(a1, bbf, acc[1], 0, 0, 0);
        }
    }
    int h = h0 + py;
#pragma unroll
    for (int r = 0; r < 4; ++r) {
        int oc = g * 4 + r;
        off[((size_t)(b * 18 + oc) << 10) + (h << 5) + px] = acc[0][r] + b_off[oc];
    }
    if (g == 0) {
#pragma unroll
        for (int r = 0; r < 2; ++r) {
            int oc = 16 + r;
            off[((size_t)(b * 18 + oc) << 10) + (h << 5) + px] = acc[1][r] + b_off[oc];
        }
    }
}

// ---------------- bilinear sampler v3: channel-pair-packed, block = (cg8, b, half) ----------------
// 576 threads = 9 waves; wave k = tap; lane = position-in-chunk.
__global__ __launch_bounds__(576) void k_sample(const float* __restrict__ x,
                                                const float* __restrict__ off,
                                                unsigned short* __restrict__ S) {
    int cg = blockIdx.x, b = blockIdx.y, half = blockIdx.z;
    int cbase = cg * 8;
    int t = threadIdx.x;
    int k = t >> 6, lane = t & 63;
    __shared__ __align__(16) unsigned int xpl[4 * 1156];   // [pair][row*36+col], 2 bf16/word
    __shared__ __align__(16) unsigned short sS[72 * 66];

    // stage 8 channels once as 4 bf16-pair planes
    for (int u = t; u < 1024; u += 576) {
        int p = u >> 8, row = (u >> 3) & 31, cq = (u & 7) << 2;
        const float* src0 = x + ((size_t)(b * 256 + cbase + 2 * p) << 10) + (row << 5) + cq;
        float4 a = *(const float4*)src0;
        float4 c = *(const float4*)(src0 + 1024);
        uint4 pk;
        pk.x = (unsigned int)f2bf(a.x) | ((unsigned int)f2bf(c.x) << 16);
        pk.y = (unsigned int)f2bf(a.y) | ((unsigned int)f2bf(c.y) << 16);
        pk.z = (unsigned int)f2bf(a.z) | ((unsigned int)f2bf(c.z) << 16);
        pk.w = (unsigned int)f2bf(a.w) | ((unsigned int)f2bf(c.w) << 16);
        *(uint4*)&xpl[p * 1156 + row * 36 + cq] = pk;
    }

    int wr_row = t / 9, wr_q = t - wr_row * 9;
    const float* offk0 = off + ((size_t)(b * 18 + 2 * k) << 10);
    const float* offk1 = off + ((size_t)(b * 18 + 2 * k + 1) << 10);
    int ky = k / 3 - 1, kx = k % 3 - 1;
    __syncthreads();

    for (int ci = 0; ci < 8; ++ci) {
        int chunk = half * 8 + ci;
        int pos = chunk * 64 + lane;
        int h = pos >> 5, w = pos & 31;
        float dy = offk0[pos];
        float dx = offk1[pos];
        float py = (float)(h + ky) + dy;
        float px = (float)(w + kx) + dx;
        float fy = floorf(py), fx = floorf(px);
        int y0i = (int)fy, x0i = (int)fx;
        float wy = py - fy, wxf = px - fx;
        float vy0 = (y0i >= 0 && y0i < 32) ? 1.f : 0.f;
        float vy1 = (y0i >= -1 && y0i < 31) ? 1.f : 0.f;
        float vx0 = (x0i >= 0 && x0i < 32) ? 1.f : 0.f;
        float vx1 = (x0i >= -1 && x0i < 31) ? 1.f : 0.f;
        int y0c = min(max(y0i, 0), 31), y1c = min(max(y0i + 1, 0), 31);
        int x0c = min(max(x0i, 0), 31), x1c = min(max(x0i + 1, 0), 31);
        float w00 = (1.f - wy) * (1.f - wxf) * vy0 * vx0;
        float w01 = (1.f - wy) * wxf * vy0 * vx1;
        float w10 = wy * (1.f - wxf) * vy1 * vx0;
        float w11 = wy * wxf * vy1 * vx1;
        int a00 = y0c * 36 + x0c, a01 = y0c * 36 + x1c;
        int a10 = y1c * 36 + x0c, a11 = y1c * 36 + x1c;
#pragma unroll
        for (int p = 0; p < 4; ++p) {
            const unsigned int* pl = xpl + p * 1156;
            unsigned int c00 = pl[a00], c01 = pl[a01], c10 = pl[a10], c11 = pl[a11];
            float e00 = __uint_as_float(c00 << 16), o00 = __uint_as_float(c00 & 0xFFFF0000u);
            float e01 = __uint_as_float(c01 << 16), o01 = __uint_as_float(c01 & 0xFFFF0000u);
            float e10 = __uint_as_float(c10 << 16), o10 = __uint_as_float(c10 & 0xFFFF0000u);
            float e11 = __uint_as_float(c11 << 16), o11 = __uint_as_float(c11 & 0xFFFF0000u);
            float ve = w00 * e00 + w01 * e01 + w10 * e10 + w11 * e11;
            float vo = w00 * o00 + w01 * o01 + w10 * o10 + w11 * o11;
            sS[((2 * p) * 9 + k) * 66 + lane] = f2bf(ve);
            sS[((2 * p + 1) * 9 + k) * 66 + lane] = f2bf(vo);
        }
        __syncthreads();
        // writer: thread = (row, q); 8 b16 reads -> one 16B global store
        {
            int basekc = wr_q * 8;
            unsigned int s0 = sS[(basekc + 0) * 66 + wr_row];
            unsigned int s1 = sS[(basekc + 1) * 66 + wr_row];
            unsigned int s2 = sS[(basekc + 2) * 66 + wr_row];
            unsigned int s3 = sS[(basekc + 3) * 66 + wr_row];
            unsigned int s4 = sS[(basekc + 4) * 66 + wr_row];
            unsigned int s5 = sS[(basekc + 5) * 66 + wr_row];
            unsigned int s6 = sS[(basekc + 6) * 66 + wr_row];
            unsigned int s7 = sS[(basekc + 7) * 66 + wr_row];
            uint4 qv;
            qv.x = s0 | (s1 << 16);
            qv.y = s2 | (s3 << 16);
            qv.z = s4 | (s5 << 16);
            qv.w = s6 | (s7 << 16);
            *(uint4*)(S + (size_t)(b * 1024 + chunk * 64 + wr_row) * 2304 + cg * 72 + wr_q * 8) = qv;
        }
        __syncthreads();
    }
}

// ---------------- GEMM1: y1[co][n] = sum_K A1[co][K] * S[n][K], K=2304 ----------------
__global__ __launch_bounds__(256) void k_gemm1(const unsigned short* __restrict__ A1,
                                               const unsigned short* __restrict__ S,
                                               const float* __restrict__ b_def,
                                               float* __restrict__ y1) {
    int nb = blockIdx.x, mb = blockIdx.y;
    int t = threadIdx.x;
    int lane = t & 63, wid = t >> 6;
    int wm = wid >> 1, wn = wid & 1;
    __shared__ __align__(16) unsigned short As[128 * 32];
    __shared__ __align__(16) unsigned short Bs[64 * 32];
    int m0 = mb * 128, n0 = nb * 64;
    float4v acc[4][2];
    float4v z = {0.f, 0.f, 0.f, 0.f};
#pragma unroll
    for (int i = 0; i < 4; ++i) { acc[i][0] = z; acc[i][1] = z; }
    int rQ = lane >> 2;
    int qA = (lane & 3) ^ ((lane >> 3) & 3);
    const unsigned short* gA0 = A1 + (size_t)(m0 + wid * 32 + rQ) * 2304 + qA * 8;
    const unsigned short* gA1 = gA0 + (size_t)16 * 2304;
    const unsigned short* gB0 = S + (size_t)(n0 + wid * 16 + rQ) * 2304 + qA * 8;
    unsigned short* lA0 = As + wid * 32 * 32;
    unsigned short* lA1 = As + (wid * 32 + 16) * 32;
    unsigned short* lB0 = Bs + wid * 16 * 32;
    int g = lane >> 4, l15 = lane & 15;
    int gs = (g ^ ((l15 >> 1) & 3)) << 4;
    for (int s = 0; s < 72; ++s) {
        __syncthreads();
        stage1k(gA0 + s * 32, lA0);
        stage1k(gA1 + s * 32, lA1);
        stage1k(gB0 + s * 32, lB0);
        __syncthreads();
        short8v a[4], bb[2];
#pragma unroll
        for (int mi = 0; mi < 4; ++mi)
            a[mi] = *(const short8v*)((const char*)As + ((wm * 64 + mi * 16 + l15) * 64 + gs));
#pragma unroll
        for (int ni = 0; ni < 2; ++ni)
            bb[ni] = *(const short8v*)((const char*)Bs + ((wn * 32 + ni * 16 + l15) * 64 + gs));
#pragma unroll
        for (int mi = 0; mi < 4; ++mi)
#pragma unroll
            for (int ni = 0; ni < 2; ++ni)
                acc[mi][ni] = __builtin_amdgcn_mfma_f32_16x16x32_bf16(a[mi], bb[ni], acc[mi][ni], 0, 0, 0);
    }
    int b = n0 >> 10;
    int posb = n0 & 1023;
#pragma unroll
    for (int mi = 0; mi < 4; ++mi) {
#pragma unroll
        for (int r = 0; r < 4; ++r) {
            int co = m0 + wm * 64 + mi * 16 + g * 4 + r;
            float bv = b_def[co];
            float* dst = y1 + ((size_t)(b * 256 + co) << 10) + posb;
#pragma unroll
            for (int ni = 0; ni < 2; ++ni)
                dst[wn * 32 + ni * 16 + l15] = acc[mi][ni][r] + bv;
        }
    }
}

// ---------------- GEMM2: convT by parity, channel-last B, K_STEP=64, fused BN2 partials ----------------
__global__ __launch_bounds__(256) void k_gemm2(const unsigned short* __restrict__ A2,
                                               const unsigned short* __restrict__ y1T,
                                               float* __restrict__ outP,
                                               float* __restrict__ pstats2) {
    int nb = blockIdx.x, mb = blockIdx.y, p = blockIdx.z;
    int ph = p >> 1, pw = p & 1;
    int t = threadIdx.x;
    int lane = t & 63, wid = t >> 6;
    int wm = wid >> 1, wn = wid & 1;
    int l15 = lane & 15, g = lane >> 4;
    __shared__ __align__(16) unsigned short As[128 * 64];
    __shared__ __align__(16) unsigned short Bs[128 * 64];
    int m0 = mb * 128, n0 = nb * 128;
    int b = n0 >> 10, pos0 = n0 & 1023, oh0 = pos0 >> 5;

    int dtab[4];
#pragma unroll
    for (int tap = 0; tap < 4; ++tap) {
        int ty = tap >> 1, tx = tap & 1;
        int dy = ph ? (1 - ty) : (-ty);
        int dx = pw ? (1 - tx) : (-tx);
        dtab[tap] = (dy * 34 + dx) * 256;
    }
    const unsigned short* srcA[4];
    const unsigned short* srcB[4];
    unsigned short* dstA[4];
    unsigned short* dstB[4];
#pragma unroll
    for (int it = 0; it < 4; ++it) {
        int idx = t + it * 256;
        int r = idx >> 3, s8 = idx & 7, c = s8 ^ (r & 7);
        srcA[it] = A2 + (size_t)(p * 256 + m0 + r) * 1024 + c * 8;
        dstA[it] = As + idx * 8;
        int ih = oh0 + (r >> 5) + 1;
        int iw = (r & 31) + 1;
        srcB[it] = y1T + ((size_t)(b * 34 + ih) * 34 + iw) * 256 + c * 8;
        dstB[it] = Bs + idx * 8;
    }

    float4v acc[4][4];
    float4v z = {0.f, 0.f, 0.f, 0.f};
#pragma unroll
    for (int i = 0; i < 4; ++i)
#pragma unroll
        for (int j = 0; j < 4; ++j) acc[i][j] = z;

    for (int step = 0; step < 16; ++step) {
        int tap = step >> 2;
        int koff = step * 64;
        int boff = dtab[tap] + (step & 3) * 64;
        __syncthreads();
#pragma unroll
        for (int it = 0; it < 4; ++it) {
            stage1k(srcA[it] + koff, dstA[it]);
            stage1k(srcB[it] + boff, dstB[it]);
        }
        __syncthreads();
#pragma unroll
        for (int kk = 0; kk < 2; ++kk) {
            short8v a[4], bb[4];
#pragma unroll
            for (int mi = 0; mi < 4; ++mi) {
                int row = wm * 64 + mi * 16 + l15;
                int slot = ((kk << 2) + g) ^ (row & 7);
                a[mi] = *(const short8v*)((const char*)As + row * 128 + slot * 16);
            }
#pragma unroll
            for (int ni = 0; ni < 4; ++ni) {
                int row = wn * 64 + ni * 16 + l15;
                int slot = ((kk << 2) + g) ^ (row & 7);
                bb[ni] = *(const short8v*)((const char*)Bs + row * 128 + slot * 16);
            }
#pragma unroll
            for (int mi = 0; mi < 4; ++mi)
#pragma unroll
                for (int ni = 0; ni < 4; ++ni)
                    acc[mi][ni] = __builtin_amdgcn_mfma_f32_16x16x32_bf16(a[mi], bb[ni], acc[mi][ni], 0, 0, 0);
        }
    }
    // coalesced unit-stride write to parity-planar outP
#pragma unroll
    for (int mi = 0; mi < 4; ++mi) {
#pragma unroll
        for (int r = 0; r < 4; ++r) {
            int co = m0 + wm * 64 + mi * 16 + g * 4 + r;
            float* dst = outP + ((size_t)((p * 16 + b) * 256 + co) << 10) + pos0;
#pragma unroll
            for (int ni = 0; ni < 4; ++ni)
                dst[wn * 64 + ni * 16 + l15] = acc[mi][ni][r];
        }
    }
    // fused BN2 partial stats: per-block (s, s2) per co, deterministic (no atomics)
    __syncthreads();
    float* sred  = (float*)As;        // [128][2]
    float* s2red = sred + 256;        // [128][2]
#pragma unroll
    for (int mi = 0; mi < 4; ++mi) {
#pragma unroll
        for (int r = 0; r < 4; ++r) {
            float s = 0.f, s2 = 0.f;
#pragma unroll
            for (int ni = 0; ni < 4; ++ni) {
                float v = acc[mi][ni][r];
                s += v;
                s2 += v * v;
            }
#pragma unroll
            for (int m = 8; m >= 1; m >>= 1) {
                s  += __shfl_xor(s, m, 64);
                s2 += __shfl_xor(s2, m, 64);
            }
            if (l15 == 0) {
                int col = wm * 64 + mi * 16 + g * 4 + r;
                sred[col * 2 + wn]  = s;
                s2red[col * 2 + wn] = s2;
            }
        }
    }
    __syncthreads();
    if (t < 128) {
        float s  = sred[t * 2] + sred[t * 2 + 1];
        float s2 = s2red[t * 2] + s2red[t * 2 + 1];
        int row = p * 128 + nb;       // 0..511
        int ch = mb * 128 + t;
        pstats2[ch * 512 + row] = s;
        pstats2[131072 + ch * 512 + row] = s2;
    }
}

// ---------------- BN stats: per-(ch,plane) partials, then finisher ----------------
__global__ __launch_bounds__(256) void k_bnstats_part(const float* __restrict__ src, int nparts,
                                                      float* __restrict__ pstats) {
    int ch = blockIdx.x, j = blockIdx.y;
    int t = threadIdx.x;
    const float* p = src + ((size_t)(j * 256 + ch) << 10);
    float4 v = *(const float4*)&p[t * 4];
    float s  = v.x + v.y + v.z + v.w;
    float s2 = v.x * v.x + v.y * v.y + v.z * v.z + v.w * v.w;
    __shared__ float rs[256], rs2[256];
    rs[t] = s; rs2[t] = s2;
    __syncthreads();
    for (int d = 128; d > 0; d >>= 1) {
        if (t < d) { rs[t] += rs[t + d]; rs2[t] += rs2[t + d]; }
        __syncthreads();
    }
    if (t == 0) {
        pstats[ch * nparts + j] = rs[0];
        pstats[256 * nparts + ch * nparts + j] = rs2[0];
    }
}

__global__ __launch_bounds__(256) void k_bnfin(const float* __restrict__ pstats, int nparts, float n,
                                               float* __restrict__ mean, float* __restrict__ rstd) {
    int ch = threadIdx.x;
    float s = 0.f, s2 = 0.f;
    for (int j = 0; j < nparts; ++j) {
        s += pstats[ch * nparts + j];
        s2 += pstats[256 * nparts + ch * nparts + j];
    }
    float m = s / n;
    float var = s2 / n - m * m;
    mean[ch] = m;
    rstd[ch] = rsqrtf(var + 1e-5f);
}

// ---------------- BN2 finisher from gemm2's per-block partials ----------------
__global__ __launch_bounds__(256) void k_bnfin2(const float* __restrict__ pstats2,
                                                float* __restrict__ mean, float* __restrict__ rstd) {
    int ch = blockIdx.x;
    int t = threadIdx.x;
    float s  = pstats2[ch * 512 + t] + pstats2[ch * 512 + 256 + t];
    float s2 = pstats2[131072 + ch * 512 + t] + pstats2[131072 + ch * 512 + 256 + t];
    __shared__ float rs[256], rs2[256];
    rs[t] = s; rs2[t] = s2;
    __syncthreads();
    for (int d = 128; d > 0; d >>= 1) {
        if (t < d) { rs[t] += rs[t + d]; rs2[t] += rs2[t + d]; }
        __syncthreads();
    }
    if (t == 0) {
        float n = 65536.f;
        float m = rs[0] / n;
        float var = rs2[0] / n - m * m;
        mean[ch] = m;
        rstd[ch] = rsqrtf(var + 1e-5f);
    }
}

// ---------------- BN+SiLU on y1 -> channel-last padded bf16 y1T[b][34][34][256] ----------------
__global__ __launch_bounds__(256) void k_bnsilu_padT(const float* __restrict__ y1,
                                                     const float* __restrict__ mean,
                                                     const float* __restrict__ rstd,
                                                     const float* __restrict__ gamma,
                                                     const float* __restrict__ beta,
                                                     unsigned short* __restrict__ y1T) {
    int py = blockIdx.x, cg = blockIdx.y, b = blockIdx.z;
    int c0 = cg * 32;
    int t = threadIdx.x;
    __shared__ unsigned short tl[32][36];
    {
        int c_l = t >> 3, px4 = (t & 7) * 4;
        int ch = c0 + c_l;
        float m = mean[ch], rs = rstd[ch], ga = gamma[ch], be = beta[ch];
        float4 v = *(const float4*)&y1[(size_t)((b * 256 + ch) << 10) + (py << 5) + px4];
        tl[c_l][px4 + 0] = f2bf(silu(ga * (v.x - m) * rs + be));
        tl[c_l][px4 + 1] = f2bf(silu(ga * (v.y - m) * rs + be));
        tl[c_l][px4 + 2] = f2bf(silu(ga * (v.z - m) * rs + be));
        tl[c_l][px4 + 3] = f2bf(silu(ga * (v.w - m) * rs + be));
    }
    __syncthreads();
    {
        int px = t >> 3, c4 = (t & 7) * 4;
        unsigned int s0 = tl[c4 + 0][px];
        unsigned int s1 = tl[c4 + 1][px];
        unsigned int s2 = tl[c4 + 2][px];
        unsigned int s3 = tl[c4 + 3][px];
        uint2 pk;
        pk.x = s0 | (s1 << 16);
        pk.y = s2 | (s3 << 16);
        *(uint2*)&y1T[((size_t)(b * 34 + py + 1) * 34 + (px + 1)) * 256 + c0 + c4] = pk;
    }
}

// ---------------- final: BN+SiLU + parity interleave -> out ----------------
__global__ __launch_bounds__(256) void k_bnsilu_out(const float* __restrict__ outP,
                                                    const float* __restrict__ mean,
                                                    const float* __restrict__ rstd,
                                                    const float* __restrict__ gamma,
                                                    const float* __restrict__ beta,
                                                    float* __restrict__ out) {
    unsigned int i = blockIdx.x * 256 + threadIdx.x;  // float4 index, 4194304 total
    int ow4 = i & 15;
    int oh = (i >> 4) & 63;
    int co = (i >> 10) & 255;
    int b  = i >> 18;
    int p0 = (oh & 1) * 2;
    int pos = ((oh >> 1) << 5) + ow4 * 2;
    const float* pl0 = outP + ((size_t)((p0 * 16 + b) * 256 + co) << 10) + pos;
    const float* pl1 = pl0 + ((size_t)16 * 256 << 10);
    float2 e = *(const float2*)pl0;
    float2 o = *(const float2*)pl1;
    float m = mean[co], rs = rstd[co], ga = gamma[co], be = beta[co];
    float4 v;
    v.x = silu(ga * (e.x - m) * rs + be);
    v.y = silu(ga * (o.x - m) * rs + be);
    v.z = silu(ga * (e.y - m) * rs + be);
    v.w = silu(ga * (o.y - m) * rs + be);
    *(float4*)&out[((size_t)(b * 256 + co) << 12) + (oh << 6) + ow4 * 4] = v;
}

extern "C" void kernel_launch(void* const* d_in, const int* in_sizes, int n_in,
                              void* d_out, int out_size, void* d_ws, size_t ws_size,
                              hipStream_t stream) {
    const float* x      = (const float*)d_in[0];
    const float* w_off  = (const float*)d_in[1];
    const float* b_off  = (const float*)d_in[2];
    const float* w_def  = (const float*)d_in[3];
    const float* b_def  = (const float*)d_in[4];
    const float* gamma1 = (const float*)d_in[5];
    const float* beta1  = (const float*)d_in[6];
    const float* w_dc   = (const float*)d_in[7];
    const float* gamma2 = (const float*)d_in[8];
    const float* beta2  = (const float*)d_in[9];
    float* out = (float*)d_out;

    char* base = (char*)d_ws;
    unsigned short* S    = (unsigned short*)base;                 // 75,497,472 B (dead after gemm1)
    float*          y1   = (float*)(base + 75497472);             // 16,777,216 B
    unsigned short* y1T  = (unsigned short*)(base + 92274688);    //  9,469,952 B (padded ch-last)
    unsigned short* A1   = (unsigned short*)(base + 101744640);   //  1,179,648 B
    unsigned short* A2   = (unsigned short*)(base + 102924288);   //  2,097,152 B
    float*          off  = (float*)(base + 105021440);            //  1,179,648 B
    float*          stats = (float*)(base + 106201088);           //  1,024 B
    float* mean1 = stats, *rstd1 = stats + 256, *mean2 = stats + 512, *rstd2 = stats + 768;
    float* pstats = off;                       // BN1 partials (32 KB), after off consumed
    float* pstats2 = off;                      // gemm2 BN2 partials (1 MB), after BN1 done
    unsigned short* xT    = (unsigned short*)base;                //  8,388,608 B (dead after off_gemm)
    unsigned short* A2off = (unsigned short*)(base + 8388608);    //    147,456 B
    float* outP = (float*)base;                // 67,108,864 B, aliases S after gemm1

    k_prep_a1<<<2304, 256, 0, stream>>>(w_def, A1);
    k_prep_a2<<<4096, 256, 0, stream>>>(w_dc, A2);
    k_prep_aoff<<<288, 256, 0, stream>>>(w_off, A2off);
    k_prep_xt<<<dim3(32, 8, 16), 256, 0, stream>>>(x, xT);
    k_off_gemm<<<dim3(16, 16), 256, 0, stream>>>(A2off, xT, b_off, off);
    k_sample<<<dim3(32, 16, 2), 576, 0, stream>>>(x, off, S);
    k_gemm1<<<dim3(256, 2), 256, 0, stream>>>(A1, S, b_def, y1);
    k_bnstats_part<<<dim3(256, 16), 256, 0, stream>>>(y1, 16, pstats);
    k_bnfin<<<1, 256, 0, stream>>>(pstats, 16, 16384.f, mean1, rstd1);
    hipMemsetAsync(y1T, 0, 9469952, stream);   // zero halo for y1T
    k_bnsilu_padT<<<dim3(32, 8, 16), 256, 0, stream>>>(y1, mean1, rstd1, gamma1, beta1, y1T);
    k_gemm2<<<dim3(128, 2, 4), 256, 0, stream>>>(A2, y1T, outP, pstats2);
    k_bnfin2<<<256, 256, 0, stream>>>(pstats2, mean2, rstd2);
    k_bnsilu_out<<<16384, 256, 0, stream>>>(outP, mean2, rstd2, gamma2, beta2, out);
}